// Round 17
// baseline (629.586 us; speedup 1.0000x reference)
//
#include <hip/hip_runtime.h>
#include <math.h>

#define NSTAGES 4
#define NCB     1024
#define SK      4096   // NSTAGES*NCB
#define D       256
#define BEAM_W  4
#define NB      4096   // N samples
#define INFF    __builtin_huge_valf()
#define RB      128    // gemm rows per block
#define CBL     256    // gemm cols per block
#define BK      32     // gemm k-tile (single-buffered; R0-proven — see lessons log)
#define NCBLK   (SK / CBL)   // 16 col-blocks

typedef unsigned long long u64;

// LESSONS LOG (measured, this session):
//   R0: single-buffer BK=32 + tki merge = 476 us/big-gemm. Best GEMM schedule.
//   R1-R6: GEMM micro-scheduling closed (dbuf spills or regresses).
//   R7: remainder GEMMs factorized via M = XC - mf*G. 1705 -> 709 us, PASSED.
//   R8: factorized msek FAILED — msek MUST be the FROZEN D-loop chain. Key-scan
//     partitioning IS exact (top-4 = set function of distinct u64s).
//   R9/R10: fused wave-private key_select PASSED. 709 -> 599 us.
//   R11/R12: step-0 must stay fused in gemm_fused (free); 512-thr split-scan regressed.
//   R13: sym-G + in-kernel Srow PASSED (592); mirror_g before gemm_fused = L2 pollution.
//   R14: reorder fixed gemm_fused (136); 4-sublist scan regressed (+30/step, registers).
//   R15: R14 order + single-list scan = 581. R16: drop XC LDS staging = 575.
//   R17 (this): fuse the 3 key_select launches into ONE beam_iter kernel (256 thr,
//     R16 internals VERBATIM, tuples live in LDS). Samples are independent across
//     iterations -> removes 2 grid-wide sync points + launch gaps + tuples round-trips.
//     Differs from failed R11 (no redundant step-0 scan) and R12 (no split-scan).
//     Zero numeric change.

// ---------------- LLVM-vectorized reduce over 256 f32, VF=8, IC=4 (FROZEN - bit-exact vs ref)
template <typename F>
__device__ __forceinline__ float xw84(F v) {
  float r[32];
#pragma unroll
  for (int l = 0; l < 32; ++l) r[l] = v(l);
  for (int i = 32; i < 256; i += 32)
#pragma unroll
    for (int l = 0; l < 32; ++l) r[l] = __fadd_rn(r[l], v(i + l));
  float w[8];
#pragma unroll
  for (int j = 0; j < 8; ++j)
    w[j] = __fadd_rn(__fadd_rn(__fadd_rn(r[j], r[8 + j]), r[16 + j]), r[24 + j]);
  float s0 = __fadd_rn(w[0], w[4]);
  float s1 = __fadd_rn(w[1], w[5]);
  float s2 = __fadd_rn(w[2], w[6]);
  float s3 = __fadd_rn(w[3], w[7]);
  float t0 = __fadd_rn(s0, s2);
  float t1 = __fadd_rn(s1, s3);
  return __fadd_rn(t0, t1);
}

// ---------------- sorted ascending top-4 insert on packed u64 (keybits<<32 | idx).
// Keys are ~250 (>0) so float order == bit order; u64 order == lex (key, idx). FROZEN ties.
__device__ __forceinline__ void ins4u(u64 v, u64 b[4]) {
  if (v < b[3]) {
    b[3] = v;
    if (b[3] < b[2]) { u64 t = b[2]; b[2] = b[3]; b[3] = t; }
    if (b[2] < b[1]) { u64 t = b[1]; b[1] = b[2]; b[2] = t; }
    if (b[1] < b[0]) { u64 t = b[0]; b[0] = b[1]; b[1] = t; }
  }
}

// 64-bit shuffle-xor via two 32-bit shuffles (HIP-overload-proof)
__device__ __forceinline__ u64 shflx64(u64 v, int m) {
  int lo = __shfl_xor((int)(unsigned)(v & 0xFFFFFFFFULL), m, 64);
  int hi = __shfl_xor((int)(unsigned)(v >> 32), m, 64);
  return ((u64)(unsigned)hi << 32) | (u64)(unsigned)lo;
}

// ---------------- cb2[j] = sum(cb[j]**2)
__global__ __launch_bounds__(256) void cb2_pw(const float* __restrict__ cb,
                                              float* __restrict__ cb2) {
  int row = blockIdx.x * 256 + threadIdx.x;
  if (row >= SK) return;
  const float* c = cb + (size_t)row * D;
  cb2[row] = xw84([&](int d) { float t = c[d]; return __fmul_rn(t, t); });
}

// ---------------- Srow[s] = sum(x[s]**2)
__global__ __launch_bounds__(256) void s0_pw(const float* __restrict__ x,
                                             float* __restrict__ Srow) {
  int row = blockIdx.x * 256 + threadIdx.x;
  if (row >= NB) return;
  const float* xr = x + (size_t)row * D;
  Srow[row] = xw84([&](int d) { float t = xr[d]; return __fmul_rn(t, t); });
}

// ---------------- Srow for remainder rows (legacy path only; FROZEN numerics)
__global__ __launch_bounds__(256) void srow_pw(const float* __restrict__ x,
                                               const float* __restrict__ cb,
                                               const int* __restrict__ tuples,
                                               int it,
                                               float* __restrict__ Srow) {
  int row = blockIdx.x * 256 + threadIdx.x;
  if (row >= NB * BEAM_W) return;
  int s = row >> 2;
  int slot = tuples[row * NSTAGES + it];
  const float* xr = x + (size_t)s * D;
  const float* cr = cb + (size_t)slot * D;
  const float mf = (float)(it + 1);
  Srow[row] = xw84([&](int d) {
    float t = __fsub_rn(xr[d], __fmul_rn(mf, cr[d]));
    return __fmul_rn(t, t);
  });
}

// ---------------- k-major transpose (FROZEN)
__global__ __launch_bounds__(256) void transpose_rem(
    const float* __restrict__ x, const float* __restrict__ cbk,
    const int* __restrict__ tuples, int it, int isStep0, int nrows,
    float* __restrict__ AT) {
  __shared__ float tile[64][65];
  const int t = threadIdx.x;
  const int r0 = blockIdx.x * 64;
  const int d0 = blockIdx.y * 64;
  const float mf = (float)(it + 1);
  {
    int r = r0 + (t & 63);
    int db = (t >> 6) * 16;
    const float* xr;
    const float* cr = nullptr;
    if (isStep0) {
      xr = x + (size_t)r * D;
    } else {
      xr = x + (size_t)(r >> 2) * D;
      cr = cbk + (size_t)tuples[r * NSTAGES + it] * D;
    }
#pragma unroll
    for (int l = 0; l < 4; ++l) {
      float4 v = *(const float4*)&xr[d0 + db + l * 4];
      if (!isStep0) {
        float4 c = *(const float4*)&cr[d0 + db + l * 4];
        v.x = __fsub_rn(v.x, __fmul_rn(mf, c.x));
        v.y = __fsub_rn(v.y, __fmul_rn(mf, c.y));
        v.z = __fsub_rn(v.z, __fmul_rn(mf, c.z));
        v.w = __fsub_rn(v.w, __fmul_rn(mf, c.w));
      }
      tile[t & 63][db + l * 4 + 0] = v.x;
      tile[t & 63][db + l * 4 + 1] = v.y;
      tile[t & 63][db + l * 4 + 2] = v.z;
      tile[t & 63][db + l * 4 + 3] = v.w;
    }
  }
  __syncthreads();
  {
    int dd = t >> 2;
    int rb = (t & 3) * 16;
    float* orow = AT + (size_t)(d0 + dd) * nrows + r0 + rb;
#pragma unroll
    for (int l = 0; l < 4; ++l) {
      float4 v = make_float4(tile[rb + l * 4 + 0][dd], tile[rb + l * 4 + 1][dd],
                             tile[rb + l * 4 + 2][dd], tile[rb + l * 4 + 3][dd]);
      *(float4*)&orow[l * 4] = v;
    }
  }
}

// ---------------- plain GEMM (R0 schedule). sym=1: skip tiles strictly below the
// diagonal (row0 >= col0+CBL) — mirror_g fills them with bit-identical values
// (fl(a*b+c) == fl(b*a+c), identical ascending-k chain).
__global__ __launch_bounds__(256, 2) void gemm_plain(
    const float* __restrict__ AT, const float* __restrict__ BT, int nrows, int sym,
    float* __restrict__ Gout) {
  const int row0 = blockIdx.y * RB;
  const int col0 = blockIdx.x * CBL;
  if (sym && row0 >= col0 + CBL) return;   // block-uniform exit, before any barrier
  __shared__ __align__(16) float AsF[BK * 128];   // 16 KB
  __shared__ __align__(16) float BsF[BK * 256];   // 32 KB
  const int tid  = threadIdx.x;
  const int wv   = tid >> 6;
  const int lane = tid & 63;
  const int tx = tid & 15, ty = tid >> 4;

  const float* aSrc[4];
  const float* bSrc[8];
#pragma unroll
  for (int c = 0; c < 4; ++c) {
    int f = (wv * 4 + c) * 256 + lane * 4;
    aSrc[c] = AT + (size_t)(f >> 7) * nrows + row0 + (f & 127);
  }
#pragma unroll
  for (int c = 0; c < 8; ++c) {
    int f = (wv * 8 + c) * 256 + lane * 4;
    bSrc[c] = BT + (size_t)(f >> 8) * SK + col0 + (f & 255);
  }

  float acc[8][16];
#pragma unroll
  for (int i = 0; i < 8; ++i)
#pragma unroll
    for (int j = 0; j < 16; ++j) acc[i][j] = 0.0f;

  for (int kt = 0; kt < D; kt += BK) {
#pragma unroll
    for (int c = 0; c < 4; ++c)
      __builtin_amdgcn_global_load_lds(
          (const __attribute__((address_space(1))) void*)aSrc[c],
          (__attribute__((address_space(3))) void*)(AsF + (wv * 4 + c) * 256), 16, 0, 0);
#pragma unroll
    for (int c = 0; c < 8; ++c)
      __builtin_amdgcn_global_load_lds(
          (const __attribute__((address_space(1))) void*)bSrc[c],
          (__attribute__((address_space(3))) void*)(BsF + (wv * 8 + c) * 256), 16, 0, 0);
#pragma unroll
    for (int c = 0; c < 4; ++c) aSrc[c] += (size_t)BK * nrows;
#pragma unroll
    for (int c = 0; c < 8; ++c) bSrc[c] += (size_t)BK * SK;
    __syncthreads();

#pragma unroll 8
    for (int k = 0; k < BK; ++k) {   // ascending k only — do not reorder
      float a[8], b[16];
      *(float4*)&a[0]  = *(const float4*)&AsF[k * 128 + ty * 4];
      *(float4*)&a[4]  = *(const float4*)&AsF[k * 128 + 64 + ty * 4];
      *(float4*)&b[0]  = *(const float4*)&BsF[k * 256 + tx * 4];
      *(float4*)&b[4]  = *(const float4*)&BsF[k * 256 + 64 + tx * 4];
      *(float4*)&b[8]  = *(const float4*)&BsF[k * 256 + 128 + tx * 4];
      *(float4*)&b[12] = *(const float4*)&BsF[k * 256 + 192 + tx * 4];
#pragma unroll
      for (int i = 0; i < 8; ++i)
#pragma unroll
        for (int j = 0; j < 16; ++j)
          acc[i][j] = __fmaf_rn(a[i], b[j], acc[i][j]);
    }
    __syncthreads();
  }

#pragma unroll
  for (int i = 0; i < 8; ++i) {
    int lrow = (i & 3) + ((i >> 2) * 64) + ty * 4;
    float* go = Gout + (size_t)(row0 + lrow) * SK + col0;
#pragma unroll
    for (int jj = 0; jj < 4; ++jj) {
      float4 v = make_float4(acc[i][jj * 4 + 0], acc[i][jj * 4 + 1],
                             acc[i][jj * 4 + 2], acc[i][jj * 4 + 3]);
      *(float4*)&go[jj * 64 + tx * 4] = v;
    }
  }
}

// ---------------- mirror the skipped lower tiles of symmetric G: G[i][j] = G[j][i].
__global__ __launch_bounds__(256) void mirror_g(float* __restrict__ G) {
  const int bi = blockIdx.x, bj = blockIdx.y;   // target 64-row / 64-col blocks
  if (((bi >> 1) * RB) < ((bj >> 2) * CBL) + CBL) return;  // target tile was computed
  __shared__ float tile[64][65];
  const int t = threadIdx.x;
  const int rr = t & 63, c0 = (t >> 6) * 16;
  {
    const float* src = G + (size_t)(bj * 64 + rr) * SK + bi * 64 + c0;
#pragma unroll
    for (int l = 0; l < 16; l += 4) {
      float4 v = *(const float4*)&src[l];
      tile[rr][c0 + l + 0] = v.x;
      tile[rr][c0 + l + 1] = v.y;
      tile[rr][c0 + l + 2] = v.z;
      tile[rr][c0 + l + 3] = v.w;
    }
  }
  __syncthreads();
  {
    float* dst = G + (size_t)(bi * 64 + rr) * SK + bj * 64 + c0;
#pragma unroll
    for (int l = 0; l < 16; l += 4) {
      float4 v = make_float4(tile[c0 + l + 0][rr], tile[c0 + l + 1][rr],
                             tile[c0 + l + 2][rr], tile[c0 + l + 3][rr]);
      *(float4*)&dst[l] = v;
    }
  }
}

// ---------------- fused GEMM (R0 schedule) + XC dump + key + top-4 (tki merge).
// R10-proven step-0 path (key/selection comes free with the GEMM epilogue).
__global__ __launch_bounds__(256, 2) void gemm_fused(
    const float* __restrict__ AT, const float* __restrict__ BT,
    const float* __restrict__ Srow, const float* __restrict__ cb2,
    const int* __restrict__ tuples, int it, int isStep0, int nrows,
    u64* __restrict__ pki, float* __restrict__ XCout) {
  __shared__ __align__(16) char smem[66560];
  float* AsF = (float*)smem;
  float* BsF = (float*)(smem + 16384);
  u64*   tki = (u64*)smem;
  const int tid  = threadIdx.x;
  const int wv   = tid >> 6;
  const int lane = tid & 63;
  const int tx = tid & 15, ty = tid >> 4;
  const int row0 = blockIdx.y * RB;
  const int col0 = blockIdx.x * CBL;

  const float* aSrc[4];
  const float* bSrc[8];
#pragma unroll
  for (int c = 0; c < 4; ++c) {
    int f = (wv * 4 + c) * 256 + lane * 4;
    aSrc[c] = AT + (size_t)(f >> 7) * nrows + row0 + (f & 127);
  }
#pragma unroll
  for (int c = 0; c < 8; ++c) {
    int f = (wv * 8 + c) * 256 + lane * 4;
    bSrc[c] = BT + (size_t)(f >> 8) * SK + col0 + (f & 255);
  }

  float acc[8][16];
#pragma unroll
  for (int i = 0; i < 8; ++i)
#pragma unroll
    for (int j = 0; j < 16; ++j) acc[i][j] = 0.0f;

  for (int kt = 0; kt < D; kt += BK) {
#pragma unroll
    for (int c = 0; c < 4; ++c)
      __builtin_amdgcn_global_load_lds(
          (const __attribute__((address_space(1))) void*)aSrc[c],
          (__attribute__((address_space(3))) void*)(AsF + (wv * 4 + c) * 256), 16, 0, 0);
#pragma unroll
    for (int c = 0; c < 8; ++c)
      __builtin_amdgcn_global_load_lds(
          (const __attribute__((address_space(1))) void*)bSrc[c],
          (__attribute__((address_space(3))) void*)(BsF + (wv * 8 + c) * 256), 16, 0, 0);
#pragma unroll
    for (int c = 0; c < 4; ++c) aSrc[c] += (size_t)BK * nrows;
#pragma unroll
    for (int c = 0; c < 8; ++c) bSrc[c] += (size_t)BK * SK;
    __syncthreads();

#pragma unroll 8
    for (int k = 0; k < BK; ++k) {   // ascending k only — do not reorder
      float a[8], b[16];
      *(float4*)&a[0]  = *(const float4*)&AsF[k * 128 + ty * 4];
      *(float4*)&a[4]  = *(const float4*)&AsF[k * 128 + 64 + ty * 4];
      *(float4*)&b[0]  = *(const float4*)&BsF[k * 256 + tx * 4];
      *(float4*)&b[4]  = *(const float4*)&BsF[k * 256 + 64 + tx * 4];
      *(float4*)&b[8]  = *(const float4*)&BsF[k * 256 + 128 + tx * 4];
      *(float4*)&b[12] = *(const float4*)&BsF[k * 256 + 192 + tx * 4];
#pragma unroll
      for (int i = 0; i < 8; ++i)
#pragma unroll
        for (int j = 0; j < 16; ++j)
          acc[i][j] = __fmaf_rn(a[i], b[j], acc[i][j]);
    }
    __syncthreads();
  }

  if (XCout) {
#pragma unroll
    for (int i = 0; i < 8; ++i) {
      int lrow = (i & 3) + ((i >> 2) * 64) + ty * 4;
      float* xo = XCout + (size_t)(row0 + lrow) * SK + col0;
#pragma unroll
      for (int jj = 0; jj < 4; ++jj) {
        float4 v = make_float4(acc[i][jj * 4 + 0], acc[i][jj * 4 + 1],
                               acc[i][jj * 4 + 2], acc[i][jj * 4 + 3]);
        *(float4*)&xo[(jj) * 64 + tx * 4] = v;
      }
    }
  }

#pragma unroll
  for (int i = 0; i < 8; ++i) {
    int lrow = (i & 3) + ((i >> 2) * 64) + ty * 4;
    int grow = row0 + lrow;
    float S = Srow[grow];
    int banned = 0;
    if (!isStep0)
      for (int a = 0; a <= it; ++a) banned |= 1 << (tuples[grow * NSTAGES + a] >> 10);
    u64 b4[4] = {~0ULL, ~0ULL, ~0ULL, ~0ULL};
#pragma unroll
    for (int j = 0; j < 16; ++j) {
      int gcol = col0 + (j & 3) + ((j >> 2) * 64) + tx * 4;
      float key = ((banned >> (gcol >> 10)) & 1)
                      ? INFF
                      : __fadd_rn(__fsub_rn(S, __fmul_rn(2.0f, acc[i][j])), cb2[gcol]);
      ins4u(((u64)__float_as_uint(key) << 32) | (unsigned)gcol, b4);
    }
#pragma unroll
    for (int s = 0; s < 4; ++s) tki[(size_t)lrow * 65 + tx * 4 + s] = b4[s];
  }
  __syncthreads();

  if (tid < RB) {
    u64 b4[4] = {~0ULL, ~0ULL, ~0ULL, ~0ULL};
    for (int t = 0; t < 16; ++t)
#pragma unroll
      for (int s = 0; s < 4; ++s) ins4u(tki[(size_t)tid * 65 + t * 4 + s], b4);
    size_t base = ((size_t)blockIdx.x * nrows + row0 + tid) * 4;
#pragma unroll
    for (int s = 0; s < 4; ++s) pki[base + s] = b4[s];
  }
}

// ---------------- merge 16 per-block top-4 lists per row -> global top-4 (exact lex)
__global__ __launch_bounds__(256) void reduce_top4(
    const u64* __restrict__ pki, int nrows, int isStep0,
    int* __restrict__ tup, int* __restrict__ cand) {
  int r = blockIdx.x * 256 + threadIdx.x;
  if (r >= nrows) return;
  u64 b4[4] = {~0ULL, ~0ULL, ~0ULL, ~0ULL};
  for (int cblk = 0; cblk < NCBLK; ++cblk) {
    size_t base = ((size_t)cblk * nrows + r) * 4;
    ins4u(pki[base + 0], b4);
    ins4u(pki[base + 1], b4);
    ins4u(pki[base + 2], b4);
    ins4u(pki[base + 3], b4);
  }
  if (isStep0) {
#pragma unroll
    for (int s = 0; s < 4; ++s)
      tup[(r * BEAM_W + s) * NSTAGES + 0] = (int)(b4[s] & 0xFFFFFFFFULL);
  } else {
#pragma unroll
    for (int s = 0; s < 4; ++s)
      cand[r * BEAM_W + s] = (int)(b4[s] & 0xFFFFFFFFULL);
  }
}

// ---------------- fused 3-iteration beam kernel (R16 key_select internals VERBATIM,
// wrapped in for(it); tuples live in LDS; only intra-block barriers between steps —
// samples proceed independently, no grid-wide sync).
__global__ __launch_bounds__(256) void beam_iter(
    const float* __restrict__ XC, const float* __restrict__ G,
    const float* __restrict__ cb2,
    const float* __restrict__ x, const float* __restrict__ cb,
    const int* __restrict__ tup0, int* __restrict__ best) {
  const int s = blockIdx.x;
  const int t = threadIdx.x;
  const int b = t >> 6, l = t & 63;
  __shared__ int   tup_s[4][NSTAGES];
  __shared__ float msek[16];
  __shared__ int   primes[16][NSTAGES];

  if (t < 16) tup_s[t >> 2][t & 3] = tup0[(s * BEAM_W + (t >> 2)) * NSTAGES + (t & 3)];
  __syncthreads();

  for (int it = 0; it < NSTAGES - 1; ++it) {
    const float mf = (float)(it + 1);
    const int slot = tup_s[b][it];
    int banned = 0;
    for (int a = 0; a <= it; ++a) banned |= 1 << (tup_s[b][a] >> 10);

    // ---- in-kernel Srow: FROZEN xw84 replica (R11-R16 validated)
    float S;
    {
      const int ll = l & 31;
      const float* xr = x + (size_t)s * D;
      const float* cr = cb + (size_t)slot * D;
      float tt = __fsub_rn(xr[ll], __fmul_rn(mf, cr[ll]));
      float rl = __fmul_rn(tt, tt);
      for (int i = 32; i < 256; i += 32) {
        float t2 = __fsub_rn(xr[ll + i], __fmul_rn(mf, cr[ll + i]));
        rl = __fadd_rn(rl, __fmul_rn(t2, t2));
      }
      int j = l & 7;
      float rj   = __shfl(rl, j, 64);
      float rj8  = __shfl(rl, j + 8, 64);
      float rj16 = __shfl(rl, j + 16, 64);
      float rj24 = __shfl(rl, j + 24, 64);
      float w = __fadd_rn(__fadd_rn(__fadd_rn(rj, rj8), rj16), rj24);
      float w0 = __shfl(w, 0, 64), w1 = __shfl(w, 1, 64);
      float w2 = __shfl(w, 2, 64), w3 = __shfl(w, 3, 64);
      float w4 = __shfl(w, 4, 64), w5 = __shfl(w, 5, 64);
      float w6 = __shfl(w, 6, 64), w7 = __shfl(w, 7, 64);
      float s0 = __fadd_rn(w0, w4);
      float s1 = __fadd_rn(w1, w5);
      float s2 = __fadd_rn(w2, w6);
      float s3 = __fadd_rn(w3, w7);
      float t0 = __fadd_rn(s0, s2);
      float t1 = __fadd_rn(s1, s3);
      S = __fadd_rn(t0, t1);
    }

    const float* gr = G + (size_t)slot * SK;
    const float* xcr = XC + (size_t)s * SK;

    // ---- key scan (R16 verbatim, single-list, XC from global): j = (i*64+l)*4 .. +3
    u64 b4[4] = {~0ULL, ~0ULL, ~0ULL, ~0ULL};
#pragma unroll 4
    for (int i = 0; i < 16; ++i) {
      int j = (i * 64 + l) * 4;
      float4 g4 = *(const float4*)&gr[j];
      float4 x4 = *(const float4*)&xcr[j];
      float4 c4 = *(const float4*)&cb2[j];
      int ban = (banned >> (j >> 10)) & 1;
      float m0 = __fsub_rn(x4.x, __fmul_rn(mf, g4.x));
      float m1 = __fsub_rn(x4.y, __fmul_rn(mf, g4.y));
      float m2 = __fsub_rn(x4.z, __fmul_rn(mf, g4.z));
      float m3 = __fsub_rn(x4.w, __fmul_rn(mf, g4.w));
      float k0 = ban ? INFF : __fadd_rn(__fsub_rn(S, __fmul_rn(2.0f, m0)), c4.x);
      float k1 = ban ? INFF : __fadd_rn(__fsub_rn(S, __fmul_rn(2.0f, m1)), c4.y);
      float k2 = ban ? INFF : __fadd_rn(__fsub_rn(S, __fmul_rn(2.0f, m2)), c4.z);
      float k3 = ban ? INFF : __fadd_rn(__fsub_rn(S, __fmul_rn(2.0f, m3)), c4.w);
      ins4u(((u64)__float_as_uint(k0) << 32) | (unsigned)(j + 0), b4);
      ins4u(((u64)__float_as_uint(k1) << 32) | (unsigned)(j + 1), b4);
      ins4u(((u64)__float_as_uint(k2) << 32) | (unsigned)(j + 2), b4);
      ins4u(((u64)__float_as_uint(k3) << 32) | (unsigned)(j + 3), b4);
    }

    // ---- wave butterfly all-reduce of top-4 (exact lex; lists disjoint at every level)
#pragma unroll
    for (int m = 1; m < 64; m <<= 1) {
      u64 o0 = shflx64(b4[0], m);
      u64 o1 = shflx64(b4[1], m);
      u64 o2 = shflx64(b4[2], m);
      u64 o3 = shflx64(b4[3], m);
      ins4u(o0, b4);
      ins4u(o1, b4);
      ins4u(o2, b4);
      ins4u(o3, b4);
    }

    // ---- mse D-loop, register-resident, shuffle reduce (bit-exact FROZEN chain)
    {
      const int L = it + 2;
#pragma unroll
      for (int pi = 0; pi < 4; ++pi) {
        const int p = b * 4 + pi;
        int tpl[NSTAGES];
        for (int a = 0; a < NSTAGES; ++a) tpl[a] = tup_s[b][a];
        tpl[it + 1] = (int)(b4[pi] & 0xFFFFFFFFULL);
        if (l == 0)
          for (int a = 0; a < NSTAGES; ++a) primes[p][a] = tpl[a];
        float v[4];
#pragma unroll
        for (int m = 0; m < 4; ++m) {
          int d = l + m * 64;
          float q = cb[(size_t)tpl[0] * D + d];
          for (int a = 1; a < L; ++a) q = __fadd_rn(q, cb[(size_t)tpl[a] * D + d]);
          float dv = __fsub_rn(x[(size_t)s * D + d], q);
          v[m] = __fmul_rn(dv, dv);
        }
        float u0 = __shfl_xor(v[0], 32, 64);
        float u1 = __shfl_xor(v[1], 32, 64);
        float u2 = __shfl_xor(v[2], 32, 64);
        float u3 = __shfl_xor(v[3], 32, 64);
        float r0 = __fadd_rn(v[0], u0);
        r0 = __fadd_rn(r0, v[1]);
        r0 = __fadd_rn(r0, u1);
        r0 = __fadd_rn(r0, v[2]);
        r0 = __fadd_rn(r0, u2);
        r0 = __fadd_rn(r0, v[3]);
        r0 = __fadd_rn(r0, u3);
        float a8  = __shfl(r0, l + 8, 64);
        float a16 = __shfl(r0, l + 16, 64);
        float a24 = __shfl(r0, l + 24, 64);
        float w = __fadd_rn(__fadd_rn(__fadd_rn(r0, a8), a16), a24);
        float w0 = __shfl(w, 0, 64), w1 = __shfl(w, 1, 64);
        float w2 = __shfl(w, 2, 64), w3 = __shfl(w, 3, 64);
        float w4 = __shfl(w, 4, 64), w5 = __shfl(w, 5, 64);
        float w6 = __shfl(w, 6, 64), w7 = __shfl(w, 7, 64);
        float s0 = __fadd_rn(w0, w4);
        float s1 = __fadd_rn(w1, w5);
        float s2 = __fadd_rn(w2, w6);
        float s3 = __fadd_rn(w3, w7);
        float t0 = __fadd_rn(s0, s2);
        float t1 = __fadd_rn(s1, s3);
        float S2 = __fadd_rn(t0, t1);
        if (l == 0) msek[p] = __fmul_rn(S2, 0.00390625f);  // /256 exact
      }
    }
    __syncthreads();   // msek + primes visible to t==0

    // ---- select (FROZEN tie rules) — updates tup_s (LDS) or writes best
    if (t == 0) {
      if (it < NSTAGES - 2) {
        bool taken[16] = {false};
        int  newt[BEAM_W][NSTAGES];
        for (int rr2 = 0; rr2 < BEAM_W; ++rr2) {
          int bp = -1; float bk = 0.0f;
          for (int p = 0; p < 16; ++p) {
            if (taken[p]) continue;
            if (bp < 0 || msek[p] < bk) { bk = msek[p]; bp = p; }  // strict <: lowest p wins ties
          }
          taken[bp] = true;
          for (int a = 0; a < NSTAGES; ++a) newt[rr2][a] = primes[bp][a];
        }
        for (int rr2 = 0; rr2 < BEAM_W; ++rr2)
          for (int a = 0; a < NSTAGES; ++a) tup_s[rr2][a] = newt[rr2][a];
      } else {
        int bp = 0; float bk = msek[0];
        for (int p = 1; p < 16; ++p)
          if (msek[p] < bk) { bk = msek[p]; bp = p; }   // argmin: first lowest
        for (int a = 0; a < NSTAGES; ++a) best[s * NSTAGES + a] = primes[bp][a];
      }
    }
    __syncthreads();   // tup_s update visible before next iteration
  }
}

// ---------------- expand 16 tuples, mse via VF8/IC4 reduce, select (legacy path only)
__global__ __launch_bounds__(256) void mse_select(const float* __restrict__ x,
                                                  const float* __restrict__ cb,
                                                  const int* __restrict__ cand,
                                                  int it,
                                                  int* __restrict__ tuples,
                                                  int* __restrict__ best) {
  const int s = blockIdx.x, tid = threadIdx.x;
  const int wv = tid >> 6, lane = tid & 63;
  __shared__ float buf[4][256];
  __shared__ float rr[4][32];
  __shared__ float msek[16];
  __shared__ int   primes[16][NSTAGES];
  const int L = it + 2;

  for (int pi = 0; pi < 4; ++pi) {
    const int p = wv * 4 + pi;
    const int b = p >> 2, c = p & 3;
    int tpl[NSTAGES];
    for (int a = 0; a < NSTAGES; ++a) tpl[a] = tuples[(s * BEAM_W + b) * NSTAGES + a];
    tpl[it + 1] = cand[(s * BEAM_W + b) * BEAM_W + c];
    if (lane == 0)
      for (int a = 0; a < NSTAGES; ++a) primes[p][a] = tpl[a];
    for (int d = lane; d < D; d += 64) {
      float q = cb[(size_t)tpl[0] * D + d];
      for (int a = 1; a < L; ++a) q = __fadd_rn(q, cb[(size_t)tpl[a] * D + d]);
      float v = __fsub_rn(x[(size_t)s * D + d], q);
      buf[wv][d] = __fmul_rn(v, v);
    }
    __syncthreads();
    if (lane < 32) {
      float r = buf[wv][lane];
      for (int i = 32; i < 256; i += 32) r = __fadd_rn(r, buf[wv][i + lane]);
      rr[wv][lane] = r;
    }
    __syncthreads();
    if (lane == 0) {
      float w[8];
#pragma unroll
      for (int j = 0; j < 8; ++j)
        w[j] = __fadd_rn(__fadd_rn(__fadd_rn(rr[wv][j], rr[wv][8 + j]), rr[wv][16 + j]),
                         rr[wv][24 + j]);
      float s0 = __fadd_rn(w[0], w[4]);
      float s1 = __fadd_rn(w[1], w[5]);
      float s2 = __fadd_rn(w[2], w[6]);
      float s3 = __fadd_rn(w[3], w[7]);
      float t0 = __fadd_rn(s0, s2);
      float t1 = __fadd_rn(s1, s3);
      float S2 = __fadd_rn(t0, t1);
      msek[p] = __fmul_rn(S2, 0.00390625f);
    }
    __syncthreads();
  }

  if (tid == 0) {
    if (it < NSTAGES - 2) {
      bool taken[16] = {false};
      int  newt[BEAM_W][NSTAGES];
      for (int r = 0; r < BEAM_W; ++r) {
        int bp = -1; float bk = 0.0f;
        for (int p = 0; p < 16; ++p) {
          if (taken[p]) continue;
          if (bp < 0 || msek[p] < bk) { bk = msek[p]; bp = p; }
        }
        taken[bp] = true;
        for (int a = 0; a < NSTAGES; ++a) newt[r][a] = primes[bp][a];
      }
      for (int r = 0; r < BEAM_W; ++r)
        for (int a = 0; a < NSTAGES; ++a) tuples[(s * BEAM_W + r) * NSTAGES + a] = newt[r][a];
    } else {
      int bp = 0; float bk = msek[0];
      for (int p = 1; p < 16; ++p)
        if (msek[p] < bk) { bk = msek[p]; bp = p; }
      for (int a = 0; a < NSTAGES; ++a) best[s * NSTAGES + a] = primes[bp][a];
    }
  }
}

// ---------------- zero the 'used' region of d_out
__global__ void zero_used(float* __restrict__ u) {
  int t = blockIdx.x * 256 + threadIdx.x;
  if (t < SK) u[t] = 0.0f;
}

// ---------------- epilogue: nsvq (or quantized) + used bitmap
__global__ __launch_bounds__(256) void finalize_kernel(const float* __restrict__ x,
                                                       const float* __restrict__ cb,
                                                       const float* __restrict__ rvec,
                                                       const int* __restrict__ best,
                                                       const int* __restrict__ tmode,
                                                       float* __restrict__ out) {
  const int i = blockIdx.x;
  const int t = threadIdx.x;
  __shared__ double s1[256], s2[256];
  const int b0 = best[i * 4 + 0], b1 = best[i * 4 + 1];
  const int b2 = best[i * 4 + 2], b3 = best[i * 4 + 3];
  float q = ((cb[(size_t)b0 * D + t] + cb[(size_t)b1 * D + t]) + cb[(size_t)b2 * D + t]) +
            cb[(size_t)b3 * D + t];
  float xv = x[(size_t)i * D + t];
  float rv = rvec[(size_t)i * D + t];
  float df = xv - q;
  s1[t] = (double)df * (double)df;
  s2[t] = (double)rv * (double)rv;
  __syncthreads();
  for (int off = 128; off; off >>= 1) {
    if (t < off) { s1[t] += s1[t + off]; s2[t] += s2[t + off]; }
    __syncthreads();
  }
  float nh = sqrtf((float)s1[0]);
  float nr = sqrtf((float)s2[0]);
  float ratio = nh / nr + 1e-12f;
  out[(size_t)i * D + t] = (*tmode != 0) ? (xv + ratio * rv) : q;
  if (t < 4) out[(size_t)NB * D + best[i * 4 + t]] = 1.0f;
}

// ----------------------------------------------------------------
extern "C" void kernel_launch(void* const* d_in, const int* in_sizes, int n_in,
                              void* d_out, int out_size, void* d_ws, size_t ws_size,
                              hipStream_t stream) {
  const float* x   = (const float*)d_in[0];
  const float* cb  = (const float*)d_in[1];
  const float* rv  = (const float*)d_in[2];
  const int*   tm  = (const int*)d_in[3];
  float*       out = (float*)d_out;

  const size_t XC_BYTES    = (size_t)NB * SK * sizeof(float);                 // 64 MB
  const size_t G_BYTES     = (size_t)SK * SK * sizeof(float);                 // 64 MB
  const size_t BT_BYTES    = (size_t)D * SK * sizeof(float);                  // 4 MB
  const size_t AT0_BYTES   = (size_t)D * NB * sizeof(float);                  // 4 MB
  const size_t ATL_BYTES   = (size_t)D * NB * BEAM_W * sizeof(float);         // 16 MB (legacy)
  const size_t PKI0_BYTES  = (size_t)NCBLK * NB * BEAM_W * sizeof(u64);       // 2.1 MB
  const size_t PKIL_BYTES  = (size_t)NCBLK * NB * BEAM_W * 4 * sizeof(u64);   // 8.4 MB (legacy)
  const size_t S_BYTES     = (size_t)NB * BEAM_W * sizeof(float);
  const size_t CB2_BYTES   = (size_t)SK * sizeof(float);
  const size_t TUP_BYTES   = (size_t)NB * BEAM_W * NSTAGES * sizeof(int);
  const size_t CAND_BYTES  = (size_t)NB * BEAM_W * BEAM_W * sizeof(int);
  const size_t BEST_BYTES  = (size_t)NB * NSTAGES * sizeof(int);
  const size_t SMALL = S_BYTES + CB2_BYTES + TUP_BYTES + CAND_BYTES + BEST_BYTES;

  const size_t NEW_TOTAL    = XC_BYTES + G_BYTES + BT_BYTES + AT0_BYTES + PKI0_BYTES + SMALL;
  const size_t LEGACY_TOTAL = PKIL_BYTES + BT_BYTES + ATL_BYTES + SMALL;

  if (ws_size >= NEW_TOTAL) {
    // ---- fast path: step-0 GEMM first (R14 order), G pipeline, single beam_iter
    char* ws = (char*)d_ws;
    float* XC   = (float*)ws;  ws += XC_BYTES;
    float* G    = (float*)ws;  ws += G_BYTES;
    float* cbT  = (float*)ws;  ws += BT_BYTES;
    float* AT   = (float*)ws;  ws += AT0_BYTES;
    u64*   pki  = (u64*)ws;    ws += PKI0_BYTES;
    float* Srow = (float*)ws;  ws += S_BYTES;
    float* cb2  = (float*)ws;  ws += CB2_BYTES;
    int*   tup  = (int*)ws;    ws += TUP_BYTES;
    int*   cand = (int*)ws;    ws += CAND_BYTES;
    int*   best = (int*)ws;

    cb2_pw<<<SK / 256, 256, 0, stream>>>(cb, cb2);
    s0_pw<<<NB / 256, 256, 0, stream>>>(x, Srow);
    transpose_rem<<<dim3(SK / 64, D / 64), 256, 0, stream>>>(cb, cb, tup, 0, 1, SK, cbT);
    transpose_rem<<<dim3(NB / 64, D / 64), 256, 0, stream>>>(x, cb, tup, 0, 1, NB, AT);

    gemm_fused<<<dim3(NCBLK, NB / RB), 256, 0, stream>>>(AT, cbT, Srow, cb2, tup, 0, 1, NB,
                                                         pki, XC);             // step0 + XC
    reduce_top4<<<NB / 256, 256, 0, stream>>>(pki, NB, 1, tup, cand);

    gemm_plain<<<dim3(NCBLK, SK / RB), 256, 0, stream>>>(cbT, cbT, SK, 1, G);  // upper+diag
    mirror_g<<<dim3(SK / 64, SK / 64), 256, 0, stream>>>(G);                   // lower tiles

    beam_iter<<<NB, 256, 0, stream>>>(XC, G, cb2, x, cb, tup, best);

    zero_used<<<SK / 256, 256, 0, stream>>>(out + (size_t)NB * D);
    finalize_kernel<<<NB, 256, 0, stream>>>(x, cb, rv, best, tm, out);
    return;
  }

  if (ws_size < LEGACY_TOTAL) return;
  // ---------------- legacy path (R0-proven) ----------------
  char* ws = (char*)d_ws;
  u64*   pki  = (u64*)ws;    ws += PKIL_BYTES;
  float* cbT  = (float*)ws;  ws += BT_BYTES;
  float* AT   = (float*)ws;  ws += ATL_BYTES;
  float* Srow = (float*)ws;  ws += S_BYTES;
  float* cb2  = (float*)ws;  ws += CB2_BYTES;
  int*   tup  = (int*)ws;    ws += TUP_BYTES;
  int*   cand = (int*)ws;    ws += CAND_BYTES;
  int*   best = (int*)ws;

  cb2_pw<<<SK / 256, 256, 0, stream>>>(cb, cb2);
  s0_pw<<<NB / 256, 256, 0, stream>>>(x, Srow);
  transpose_rem<<<dim3(SK / 64, D / 64), 256, 0, stream>>>(cb, cb, tup, 0, 1, SK, cbT);
  transpose_rem<<<dim3(NB / 64, D / 64), 256, 0, stream>>>(x, cb, tup, 0, 1, NB, AT);

  gemm_fused<<<dim3(NCBLK, NB / RB), 256, 0, stream>>>(AT, cbT, Srow, cb2, tup, 0, 1, NB,
                                                       pki, nullptr);
  reduce_top4<<<NB / 256, 256, 0, stream>>>(pki, NB, 1, tup, cand);

  for (int it = 0; it < NSTAGES - 1; ++it) {
    srow_pw<<<(NB * BEAM_W) / 256, 256, 0, stream>>>(x, cb, tup, it, Srow);
    transpose_rem<<<dim3(NB * BEAM_W / 64, D / 64), 256, 0, stream>>>(x, cb, tup, it, 0,
                                                                      NB * BEAM_W, AT);
    gemm_fused<<<dim3(NCBLK, (NB * BEAM_W) / RB), 256, 0, stream>>>(
        AT, cbT, Srow, cb2, tup, it, 0, NB * BEAM_W, pki, nullptr);
    reduce_top4<<<(NB * BEAM_W) / 256, 256, 0, stream>>>(pki, NB * BEAM_W, 0, tup, cand);
    mse_select<<<NB, 256, 0, stream>>>(x, cb, cand, it, tup, best);
  }

  zero_used<<<SK / 256, 256, 0, stream>>>(out + (size_t)NB * D);
  finalize_kernel<<<NB, 256, 0, stream>>>(x, cb, rv, best, tm, out);
}

// Round 18
// 577.838 us; speedup vs baseline: 1.0896x; 1.0896x over previous
//
#include <hip/hip_runtime.h>
#include <math.h>

#define NSTAGES 4
#define NCB     1024
#define SK      4096   // NSTAGES*NCB
#define D       256
#define BEAM_W  4
#define NB      4096   // N samples
#define INFF    __builtin_huge_valf()
#define RB      128    // gemm rows per block
#define CBL     256    // gemm cols per block
#define BK      32     // gemm k-tile (single-buffered; R0-proven — see lessons log)
#define NCBLK   (SK / CBL)   // 16 col-blocks

typedef unsigned long long u64;

// LESSONS LOG (measured, this session):
//   R0: single-buffer BK=32 + tki merge = 476 us/big-gemm. Best GEMM schedule.
//   R1-R6: GEMM micro-scheduling closed (dbuf spills or regresses).
//   R7: remainder GEMMs factorized via M = XC - mf*G. 1705 -> 709 us, PASSED.
//   R8: factorized msek FAILED — msek MUST be the FROZEN D-loop chain. Key-scan
//     partitioning IS exact (top-4 = set function of distinct u64s).
//   R9/R10: fused wave-private key_select PASSED. 709 -> 599 us.
//   R11/R12: step-0 must stay fused in gemm_fused (free); 512-thr split-scan regressed.
//   R13: sym-G + in-kernel Srow PASSED (592); mirror_g before gemm_fused = L2 pollution.
//   R14: reorder fixed gemm_fused (136); 4-sublist scan regressed (+30/step, registers).
//   R15: R14 order + single-list scan = 581. R16: drop XC LDS staging = 575. BEST.
//   R17: fusing 3 key_select launches into one beam_iter REGRESSED (297 vs 246 us):
//     tripled per-block critical path outweighs saved grid syncs. Beam phase is
//     optimal as 3 short 256-thread launches. ALL beam restructurings closed
//     (R11 refusion, R12 split-scan, R17 iteration-fusion all lost to R16).
//   R18 (this): revert to R16 verbatim — session-best configuration.

// ---------------- LLVM-vectorized reduce over 256 f32, VF=8, IC=4 (FROZEN - bit-exact vs ref)
template <typename F>
__device__ __forceinline__ float xw84(F v) {
  float r[32];
#pragma unroll
  for (int l = 0; l < 32; ++l) r[l] = v(l);
  for (int i = 32; i < 256; i += 32)
#pragma unroll
    for (int l = 0; l < 32; ++l) r[l] = __fadd_rn(r[l], v(i + l));
  float w[8];
#pragma unroll
  for (int j = 0; j < 8; ++j)
    w[j] = __fadd_rn(__fadd_rn(__fadd_rn(r[j], r[8 + j]), r[16 + j]), r[24 + j]);
  float s0 = __fadd_rn(w[0], w[4]);
  float s1 = __fadd_rn(w[1], w[5]);
  float s2 = __fadd_rn(w[2], w[6]);
  float s3 = __fadd_rn(w[3], w[7]);
  float t0 = __fadd_rn(s0, s2);
  float t1 = __fadd_rn(s1, s3);
  return __fadd_rn(t0, t1);
}

// ---------------- sorted ascending top-4 insert on packed u64 (keybits<<32 | idx).
// Keys are ~250 (>0) so float order == bit order; u64 order == lex (key, idx). FROZEN ties.
__device__ __forceinline__ void ins4u(u64 v, u64 b[4]) {
  if (v < b[3]) {
    b[3] = v;
    if (b[3] < b[2]) { u64 t = b[2]; b[2] = b[3]; b[3] = t; }
    if (b[2] < b[1]) { u64 t = b[1]; b[1] = b[2]; b[2] = t; }
    if (b[1] < b[0]) { u64 t = b[0]; b[0] = b[1]; b[1] = t; }
  }
}

// 64-bit shuffle-xor via two 32-bit shuffles (HIP-overload-proof)
__device__ __forceinline__ u64 shflx64(u64 v, int m) {
  int lo = __shfl_xor((int)(unsigned)(v & 0xFFFFFFFFULL), m, 64);
  int hi = __shfl_xor((int)(unsigned)(v >> 32), m, 64);
  return ((u64)(unsigned)hi << 32) | (u64)(unsigned)lo;
}

// ---------------- cb2[j] = sum(cb[j]**2)
__global__ __launch_bounds__(256) void cb2_pw(const float* __restrict__ cb,
                                              float* __restrict__ cb2) {
  int row = blockIdx.x * 256 + threadIdx.x;
  if (row >= SK) return;
  const float* c = cb + (size_t)row * D;
  cb2[row] = xw84([&](int d) { float t = c[d]; return __fmul_rn(t, t); });
}

// ---------------- Srow[s] = sum(x[s]**2)
__global__ __launch_bounds__(256) void s0_pw(const float* __restrict__ x,
                                             float* __restrict__ Srow) {
  int row = blockIdx.x * 256 + threadIdx.x;
  if (row >= NB) return;
  const float* xr = x + (size_t)row * D;
  Srow[row] = xw84([&](int d) { float t = xr[d]; return __fmul_rn(t, t); });
}

// ---------------- Srow for remainder rows (legacy path only; FROZEN numerics)
__global__ __launch_bounds__(256) void srow_pw(const float* __restrict__ x,
                                               const float* __restrict__ cb,
                                               const int* __restrict__ tuples,
                                               int it,
                                               float* __restrict__ Srow) {
  int row = blockIdx.x * 256 + threadIdx.x;
  if (row >= NB * BEAM_W) return;
  int s = row >> 2;
  int slot = tuples[row * NSTAGES + it];
  const float* xr = x + (size_t)s * D;
  const float* cr = cb + (size_t)slot * D;
  const float mf = (float)(it + 1);
  Srow[row] = xw84([&](int d) {
    float t = __fsub_rn(xr[d], __fmul_rn(mf, cr[d]));
    return __fmul_rn(t, t);
  });
}

// ---------------- k-major transpose (FROZEN)
__global__ __launch_bounds__(256) void transpose_rem(
    const float* __restrict__ x, const float* __restrict__ cbk,
    const int* __restrict__ tuples, int it, int isStep0, int nrows,
    float* __restrict__ AT) {
  __shared__ float tile[64][65];
  const int t = threadIdx.x;
  const int r0 = blockIdx.x * 64;
  const int d0 = blockIdx.y * 64;
  const float mf = (float)(it + 1);
  {
    int r = r0 + (t & 63);
    int db = (t >> 6) * 16;
    const float* xr;
    const float* cr = nullptr;
    if (isStep0) {
      xr = x + (size_t)r * D;
    } else {
      xr = x + (size_t)(r >> 2) * D;
      cr = cbk + (size_t)tuples[r * NSTAGES + it] * D;
    }
#pragma unroll
    for (int l = 0; l < 4; ++l) {
      float4 v = *(const float4*)&xr[d0 + db + l * 4];
      if (!isStep0) {
        float4 c = *(const float4*)&cr[d0 + db + l * 4];
        v.x = __fsub_rn(v.x, __fmul_rn(mf, c.x));
        v.y = __fsub_rn(v.y, __fmul_rn(mf, c.y));
        v.z = __fsub_rn(v.z, __fmul_rn(mf, c.z));
        v.w = __fsub_rn(v.w, __fmul_rn(mf, c.w));
      }
      tile[t & 63][db + l * 4 + 0] = v.x;
      tile[t & 63][db + l * 4 + 1] = v.y;
      tile[t & 63][db + l * 4 + 2] = v.z;
      tile[t & 63][db + l * 4 + 3] = v.w;
    }
  }
  __syncthreads();
  {
    int dd = t >> 2;
    int rb = (t & 3) * 16;
    float* orow = AT + (size_t)(d0 + dd) * nrows + r0 + rb;
#pragma unroll
    for (int l = 0; l < 4; ++l) {
      float4 v = make_float4(tile[rb + l * 4 + 0][dd], tile[rb + l * 4 + 1][dd],
                             tile[rb + l * 4 + 2][dd], tile[rb + l * 4 + 3][dd]);
      *(float4*)&orow[l * 4] = v;
    }
  }
}

// ---------------- plain GEMM (R0 schedule). sym=1: skip tiles strictly below the
// diagonal (row0 >= col0+CBL) — mirror_g fills them with bit-identical values
// (fl(a*b+c) == fl(b*a+c), identical ascending-k chain).
__global__ __launch_bounds__(256, 2) void gemm_plain(
    const float* __restrict__ AT, const float* __restrict__ BT, int nrows, int sym,
    float* __restrict__ Gout) {
  const int row0 = blockIdx.y * RB;
  const int col0 = blockIdx.x * CBL;
  if (sym && row0 >= col0 + CBL) return;   // block-uniform exit, before any barrier
  __shared__ __align__(16) float AsF[BK * 128];   // 16 KB
  __shared__ __align__(16) float BsF[BK * 256];   // 32 KB
  const int tid  = threadIdx.x;
  const int wv   = tid >> 6;
  const int lane = tid & 63;
  const int tx = tid & 15, ty = tid >> 4;

  const float* aSrc[4];
  const float* bSrc[8];
#pragma unroll
  for (int c = 0; c < 4; ++c) {
    int f = (wv * 4 + c) * 256 + lane * 4;
    aSrc[c] = AT + (size_t)(f >> 7) * nrows + row0 + (f & 127);
  }
#pragma unroll
  for (int c = 0; c < 8; ++c) {
    int f = (wv * 8 + c) * 256 + lane * 4;
    bSrc[c] = BT + (size_t)(f >> 8) * SK + col0 + (f & 255);
  }

  float acc[8][16];
#pragma unroll
  for (int i = 0; i < 8; ++i)
#pragma unroll
    for (int j = 0; j < 16; ++j) acc[i][j] = 0.0f;

  for (int kt = 0; kt < D; kt += BK) {
#pragma unroll
    for (int c = 0; c < 4; ++c)
      __builtin_amdgcn_global_load_lds(
          (const __attribute__((address_space(1))) void*)aSrc[c],
          (__attribute__((address_space(3))) void*)(AsF + (wv * 4 + c) * 256), 16, 0, 0);
#pragma unroll
    for (int c = 0; c < 8; ++c)
      __builtin_amdgcn_global_load_lds(
          (const __attribute__((address_space(1))) void*)bSrc[c],
          (__attribute__((address_space(3))) void*)(BsF + (wv * 8 + c) * 256), 16, 0, 0);
#pragma unroll
    for (int c = 0; c < 4; ++c) aSrc[c] += (size_t)BK * nrows;
#pragma unroll
    for (int c = 0; c < 8; ++c) bSrc[c] += (size_t)BK * SK;
    __syncthreads();

#pragma unroll 8
    for (int k = 0; k < BK; ++k) {   // ascending k only — do not reorder
      float a[8], b[16];
      *(float4*)&a[0]  = *(const float4*)&AsF[k * 128 + ty * 4];
      *(float4*)&a[4]  = *(const float4*)&AsF[k * 128 + 64 + ty * 4];
      *(float4*)&b[0]  = *(const float4*)&BsF[k * 256 + tx * 4];
      *(float4*)&b[4]  = *(const float4*)&BsF[k * 256 + 64 + tx * 4];
      *(float4*)&b[8]  = *(const float4*)&BsF[k * 256 + 128 + tx * 4];
      *(float4*)&b[12] = *(const float4*)&BsF[k * 256 + 192 + tx * 4];
#pragma unroll
      for (int i = 0; i < 8; ++i)
#pragma unroll
        for (int j = 0; j < 16; ++j)
          acc[i][j] = __fmaf_rn(a[i], b[j], acc[i][j]);
    }
    __syncthreads();
  }

#pragma unroll
  for (int i = 0; i < 8; ++i) {
    int lrow = (i & 3) + ((i >> 2) * 64) + ty * 4;
    float* go = Gout + (size_t)(row0 + lrow) * SK + col0;
#pragma unroll
    for (int jj = 0; jj < 4; ++jj) {
      float4 v = make_float4(acc[i][jj * 4 + 0], acc[i][jj * 4 + 1],
                             acc[i][jj * 4 + 2], acc[i][jj * 4 + 3]);
      *(float4*)&go[jj * 64 + tx * 4] = v;
    }
  }
}

// ---------------- mirror the skipped lower tiles of symmetric G: G[i][j] = G[j][i].
__global__ __launch_bounds__(256) void mirror_g(float* __restrict__ G) {
  const int bi = blockIdx.x, bj = blockIdx.y;   // target 64-row / 64-col blocks
  if (((bi >> 1) * RB) < ((bj >> 2) * CBL) + CBL) return;  // target tile was computed
  __shared__ float tile[64][65];
  const int t = threadIdx.x;
  const int rr = t & 63, c0 = (t >> 6) * 16;
  {
    const float* src = G + (size_t)(bj * 64 + rr) * SK + bi * 64 + c0;
#pragma unroll
    for (int l = 0; l < 16; l += 4) {
      float4 v = *(const float4*)&src[l];
      tile[rr][c0 + l + 0] = v.x;
      tile[rr][c0 + l + 1] = v.y;
      tile[rr][c0 + l + 2] = v.z;
      tile[rr][c0 + l + 3] = v.w;
    }
  }
  __syncthreads();
  {
    float* dst = G + (size_t)(bi * 64 + rr) * SK + bj * 64 + c0;
#pragma unroll
    for (int l = 0; l < 16; l += 4) {
      float4 v = make_float4(tile[c0 + l + 0][rr], tile[c0 + l + 1][rr],
                             tile[c0 + l + 2][rr], tile[c0 + l + 3][rr]);
      *(float4*)&dst[l] = v;
    }
  }
}

// ---------------- fused GEMM (R0 schedule) + XC dump + key + top-4 (tki merge).
// R10-proven step-0 path (key/selection comes free with the GEMM epilogue).
__global__ __launch_bounds__(256, 2) void gemm_fused(
    const float* __restrict__ AT, const float* __restrict__ BT,
    const float* __restrict__ Srow, const float* __restrict__ cb2,
    const int* __restrict__ tuples, int it, int isStep0, int nrows,
    u64* __restrict__ pki, float* __restrict__ XCout) {
  __shared__ __align__(16) char smem[66560];
  float* AsF = (float*)smem;
  float* BsF = (float*)(smem + 16384);
  u64*   tki = (u64*)smem;
  const int tid  = threadIdx.x;
  const int wv   = tid >> 6;
  const int lane = tid & 63;
  const int tx = tid & 15, ty = tid >> 4;
  const int row0 = blockIdx.y * RB;
  const int col0 = blockIdx.x * CBL;

  const float* aSrc[4];
  const float* bSrc[8];
#pragma unroll
  for (int c = 0; c < 4; ++c) {
    int f = (wv * 4 + c) * 256 + lane * 4;
    aSrc[c] = AT + (size_t)(f >> 7) * nrows + row0 + (f & 127);
  }
#pragma unroll
  for (int c = 0; c < 8; ++c) {
    int f = (wv * 8 + c) * 256 + lane * 4;
    bSrc[c] = BT + (size_t)(f >> 8) * SK + col0 + (f & 255);
  }

  float acc[8][16];
#pragma unroll
  for (int i = 0; i < 8; ++i)
#pragma unroll
    for (int j = 0; j < 16; ++j) acc[i][j] = 0.0f;

  for (int kt = 0; kt < D; kt += BK) {
#pragma unroll
    for (int c = 0; c < 4; ++c)
      __builtin_amdgcn_global_load_lds(
          (const __attribute__((address_space(1))) void*)aSrc[c],
          (__attribute__((address_space(3))) void*)(AsF + (wv * 4 + c) * 256), 16, 0, 0);
#pragma unroll
    for (int c = 0; c < 8; ++c)
      __builtin_amdgcn_global_load_lds(
          (const __attribute__((address_space(1))) void*)bSrc[c],
          (__attribute__((address_space(3))) void*)(BsF + (wv * 8 + c) * 256), 16, 0, 0);
#pragma unroll
    for (int c = 0; c < 4; ++c) aSrc[c] += (size_t)BK * nrows;
#pragma unroll
    for (int c = 0; c < 8; ++c) bSrc[c] += (size_t)BK * SK;
    __syncthreads();

#pragma unroll 8
    for (int k = 0; k < BK; ++k) {   // ascending k only — do not reorder
      float a[8], b[16];
      *(float4*)&a[0]  = *(const float4*)&AsF[k * 128 + ty * 4];
      *(float4*)&a[4]  = *(const float4*)&AsF[k * 128 + 64 + ty * 4];
      *(float4*)&b[0]  = *(const float4*)&BsF[k * 256 + tx * 4];
      *(float4*)&b[4]  = *(const float4*)&BsF[k * 256 + 64 + tx * 4];
      *(float4*)&b[8]  = *(const float4*)&BsF[k * 256 + 128 + tx * 4];
      *(float4*)&b[12] = *(const float4*)&BsF[k * 256 + 192 + tx * 4];
#pragma unroll
      for (int i = 0; i < 8; ++i)
#pragma unroll
        for (int j = 0; j < 16; ++j)
          acc[i][j] = __fmaf_rn(a[i], b[j], acc[i][j]);
    }
    __syncthreads();
  }

  if (XCout) {
#pragma unroll
    for (int i = 0; i < 8; ++i) {
      int lrow = (i & 3) + ((i >> 2) * 64) + ty * 4;
      float* xo = XCout + (size_t)(row0 + lrow) * SK + col0;
#pragma unroll
      for (int jj = 0; jj < 4; ++jj) {
        float4 v = make_float4(acc[i][jj * 4 + 0], acc[i][jj * 4 + 1],
                               acc[i][jj * 4 + 2], acc[i][jj * 4 + 3]);
        *(float4*)&xo[(jj) * 64 + tx * 4] = v;
      }
    }
  }

#pragma unroll
  for (int i = 0; i < 8; ++i) {
    int lrow = (i & 3) + ((i >> 2) * 64) + ty * 4;
    int grow = row0 + lrow;
    float S = Srow[grow];
    int banned = 0;
    if (!isStep0)
      for (int a = 0; a <= it; ++a) banned |= 1 << (tuples[grow * NSTAGES + a] >> 10);
    u64 b4[4] = {~0ULL, ~0ULL, ~0ULL, ~0ULL};
#pragma unroll
    for (int j = 0; j < 16; ++j) {
      int gcol = col0 + (j & 3) + ((j >> 2) * 64) + tx * 4;
      float key = ((banned >> (gcol >> 10)) & 1)
                      ? INFF
                      : __fadd_rn(__fsub_rn(S, __fmul_rn(2.0f, acc[i][j])), cb2[gcol]);
      ins4u(((u64)__float_as_uint(key) << 32) | (unsigned)gcol, b4);
    }
#pragma unroll
    for (int s = 0; s < 4; ++s) tki[(size_t)lrow * 65 + tx * 4 + s] = b4[s];
  }
  __syncthreads();

  if (tid < RB) {
    u64 b4[4] = {~0ULL, ~0ULL, ~0ULL, ~0ULL};
    for (int t = 0; t < 16; ++t)
#pragma unroll
      for (int s = 0; s < 4; ++s) ins4u(tki[(size_t)tid * 65 + t * 4 + s], b4);
    size_t base = ((size_t)blockIdx.x * nrows + row0 + tid) * 4;
#pragma unroll
    for (int s = 0; s < 4; ++s) pki[base + s] = b4[s];
  }
}

// ---------------- merge 16 per-block top-4 lists per row -> global top-4 (exact lex)
__global__ __launch_bounds__(256) void reduce_top4(
    const u64* __restrict__ pki, int nrows, int isStep0,
    int* __restrict__ tup, int* __restrict__ cand) {
  int r = blockIdx.x * 256 + threadIdx.x;
  if (r >= nrows) return;
  u64 b4[4] = {~0ULL, ~0ULL, ~0ULL, ~0ULL};
  for (int cblk = 0; cblk < NCBLK; ++cblk) {
    size_t base = ((size_t)cblk * nrows + r) * 4;
    ins4u(pki[base + 0], b4);
    ins4u(pki[base + 1], b4);
    ins4u(pki[base + 2], b4);
    ins4u(pki[base + 3], b4);
  }
  if (isStep0) {
#pragma unroll
    for (int s = 0; s < 4; ++s)
      tup[(r * BEAM_W + s) * NSTAGES + 0] = (int)(b4[s] & 0xFFFFFFFFULL);
  } else {
#pragma unroll
    for (int s = 0; s < 4; ++s)
      cand[r * BEAM_W + s] = (int)(b4[s] & 0xFFFFFFFFULL);
  }
}

// ---------------- fused per-step kernel (R16 structure, NO XC LDS staging —
// XC row is L3-resident and read once per wave; stage-only-if-not-cache-fit):
// in-kernel Srow (FROZEN replica) + factorized keys (single-list scan) +
// butterfly top-4 (exact) + shuffle-based mse (FROZEN chain) + select.
__global__ __launch_bounds__(256) void key_select(
    const float* __restrict__ XC, const float* __restrict__ G,
    const float* __restrict__ cb2,
    const float* __restrict__ x, const float* __restrict__ cb,
    int it, int* __restrict__ tuples, int* __restrict__ best) {
  const int s = blockIdx.x;
  const int t = threadIdx.x;
  const int b = t >> 6, l = t & 63;
  __shared__ int   tup_s[4][NSTAGES];
  __shared__ float msek[16];
  __shared__ int   primes[16][NSTAGES];

  if (t < 16) tup_s[t >> 2][t & 3] = tuples[(s * BEAM_W + (t >> 2)) * NSTAGES + (t & 3)];
  __syncthreads();   // barrier 1: tup_s visible to all waves

  const float mf = (float)(it + 1);
  const int slot = tup_s[b][it];
  int banned = 0;
  for (int a = 0; a <= it; ++a) banned |= 1 << (tup_s[b][a] >> 10);

  // ---- in-kernel Srow: FROZEN xw84 replica (R11-R16 validated)
  float S;
  {
    const int ll = l & 31;
    const float* xr = x + (size_t)s * D;
    const float* cr = cb + (size_t)slot * D;
    float tt = __fsub_rn(xr[ll], __fmul_rn(mf, cr[ll]));
    float rl = __fmul_rn(tt, tt);
    for (int i = 32; i < 256; i += 32) {
      float t2 = __fsub_rn(xr[ll + i], __fmul_rn(mf, cr[ll + i]));
      rl = __fadd_rn(rl, __fmul_rn(t2, t2));
    }
    int j = l & 7;
    float rj   = __shfl(rl, j, 64);
    float rj8  = __shfl(rl, j + 8, 64);
    float rj16 = __shfl(rl, j + 16, 64);
    float rj24 = __shfl(rl, j + 24, 64);
    float w = __fadd_rn(__fadd_rn(__fadd_rn(rj, rj8), rj16), rj24);
    float w0 = __shfl(w, 0, 64), w1 = __shfl(w, 1, 64);
    float w2 = __shfl(w, 2, 64), w3 = __shfl(w, 3, 64);
    float w4 = __shfl(w, 4, 64), w5 = __shfl(w, 5, 64);
    float w6 = __shfl(w, 6, 64), w7 = __shfl(w, 7, 64);
    float s0 = __fadd_rn(w0, w4);
    float s1 = __fadd_rn(w1, w5);
    float s2 = __fadd_rn(w2, w6);
    float s3 = __fadd_rn(w3, w7);
    float t0 = __fadd_rn(s0, s2);
    float t1 = __fadd_rn(s1, s3);
    S = __fadd_rn(t0, t1);
  }

  const float* gr = G + (size_t)slot * SK;
  const float* xcr = XC + (size_t)s * SK;

  // ---- key scan (single-list, XC from global): j = (i*64+l)*4 .. +3
  u64 b4[4] = {~0ULL, ~0ULL, ~0ULL, ~0ULL};
#pragma unroll 4
  for (int i = 0; i < 16; ++i) {
    int j = (i * 64 + l) * 4;
    float4 g4 = *(const float4*)&gr[j];
    float4 x4 = *(const float4*)&xcr[j];
    float4 c4 = *(const float4*)&cb2[j];
    int ban = (banned >> (j >> 10)) & 1;
    float m0 = __fsub_rn(x4.x, __fmul_rn(mf, g4.x));
    float m1 = __fsub_rn(x4.y, __fmul_rn(mf, g4.y));
    float m2 = __fsub_rn(x4.z, __fmul_rn(mf, g4.z));
    float m3 = __fsub_rn(x4.w, __fmul_rn(mf, g4.w));
    float k0 = ban ? INFF : __fadd_rn(__fsub_rn(S, __fmul_rn(2.0f, m0)), c4.x);
    float k1 = ban ? INFF : __fadd_rn(__fsub_rn(S, __fmul_rn(2.0f, m1)), c4.y);
    float k2 = ban ? INFF : __fadd_rn(__fsub_rn(S, __fmul_rn(2.0f, m2)), c4.z);
    float k3 = ban ? INFF : __fadd_rn(__fsub_rn(S, __fmul_rn(2.0f, m3)), c4.w);
    ins4u(((u64)__float_as_uint(k0) << 32) | (unsigned)(j + 0), b4);
    ins4u(((u64)__float_as_uint(k1) << 32) | (unsigned)(j + 1), b4);
    ins4u(((u64)__float_as_uint(k2) << 32) | (unsigned)(j + 2), b4);
    ins4u(((u64)__float_as_uint(k3) << 32) | (unsigned)(j + 3), b4);
  }

  // ---- wave butterfly all-reduce of top-4 (exact lex; lists disjoint at every level)
#pragma unroll
  for (int m = 1; m < 64; m <<= 1) {
    u64 o0 = shflx64(b4[0], m);
    u64 o1 = shflx64(b4[1], m);
    u64 o2 = shflx64(b4[2], m);
    u64 o3 = shflx64(b4[3], m);
    ins4u(o0, b4);
    ins4u(o1, b4);
    ins4u(o2, b4);
    ins4u(o3, b4);
  }

  // ---- mse D-loop, register-resident, shuffle reduce (bit-exact FROZEN chain)
  {
    const int L = it + 2;
#pragma unroll
    for (int pi = 0; pi < 4; ++pi) {
      const int p = b * 4 + pi;
      int tpl[NSTAGES];
      for (int a = 0; a < NSTAGES; ++a) tpl[a] = tup_s[b][a];
      tpl[it + 1] = (int)(b4[pi] & 0xFFFFFFFFULL);
      if (l == 0)
        for (int a = 0; a < NSTAGES; ++a) primes[p][a] = tpl[a];
      float v[4];
#pragma unroll
      for (int m = 0; m < 4; ++m) {
        int d = l + m * 64;
        float q = cb[(size_t)tpl[0] * D + d];
        for (int a = 1; a < L; ++a) q = __fadd_rn(q, cb[(size_t)tpl[a] * D + d]);
        float dv = __fsub_rn(x[(size_t)s * D + d], q);
        v[m] = __fmul_rn(dv, dv);
      }
      float u0 = __shfl_xor(v[0], 32, 64);
      float u1 = __shfl_xor(v[1], 32, 64);
      float u2 = __shfl_xor(v[2], 32, 64);
      float u3 = __shfl_xor(v[3], 32, 64);
      float r0 = __fadd_rn(v[0], u0);
      r0 = __fadd_rn(r0, v[1]);
      r0 = __fadd_rn(r0, u1);
      r0 = __fadd_rn(r0, v[2]);
      r0 = __fadd_rn(r0, u2);
      r0 = __fadd_rn(r0, v[3]);
      r0 = __fadd_rn(r0, u3);
      float a8  = __shfl(r0, l + 8, 64);
      float a16 = __shfl(r0, l + 16, 64);
      float a24 = __shfl(r0, l + 24, 64);
      float w = __fadd_rn(__fadd_rn(__fadd_rn(r0, a8), a16), a24);
      float w0 = __shfl(w, 0, 64), w1 = __shfl(w, 1, 64);
      float w2 = __shfl(w, 2, 64), w3 = __shfl(w, 3, 64);
      float w4 = __shfl(w, 4, 64), w5 = __shfl(w, 5, 64);
      float w6 = __shfl(w, 6, 64), w7 = __shfl(w, 7, 64);
      float s0 = __fadd_rn(w0, w4);
      float s1 = __fadd_rn(w1, w5);
      float s2 = __fadd_rn(w2, w6);
      float s3 = __fadd_rn(w3, w7);
      float t0 = __fadd_rn(s0, s2);
      float t1 = __fadd_rn(s1, s3);
      float S2 = __fadd_rn(t0, t1);
      if (l == 0) msek[p] = __fmul_rn(S2, 0.00390625f);  // /256 exact
    }
  }
  __syncthreads();   // barrier 2: msek + primes visible to t==0

  if (t == 0) {
    if (it < NSTAGES - 2) {
      bool taken[16] = {false};
      int  newt[BEAM_W][NSTAGES];
      for (int rr2 = 0; rr2 < BEAM_W; ++rr2) {
        int bp = -1; float bk = 0.0f;
        for (int p = 0; p < 16; ++p) {
          if (taken[p]) continue;
          if (bp < 0 || msek[p] < bk) { bk = msek[p]; bp = p; }  // strict <: lowest p wins ties
        }
        taken[bp] = true;
        for (int a = 0; a < NSTAGES; ++a) newt[rr2][a] = primes[bp][a];
      }
      for (int rr2 = 0; rr2 < BEAM_W; ++rr2)
        for (int a = 0; a < NSTAGES; ++a)
          tuples[(s * BEAM_W + rr2) * NSTAGES + a] = newt[rr2][a];
    } else {
      int bp = 0; float bk = msek[0];
      for (int p = 1; p < 16; ++p)
        if (msek[p] < bk) { bk = msek[p]; bp = p; }   // argmin: first lowest
      for (int a = 0; a < NSTAGES; ++a) best[s * NSTAGES + a] = primes[bp][a];
    }
  }
}

// ---------------- expand 16 tuples, mse via VF8/IC4 reduce, select (legacy path only)
__global__ __launch_bounds__(256) void mse_select(const float* __restrict__ x,
                                                  const float* __restrict__ cb,
                                                  const int* __restrict__ cand,
                                                  int it,
                                                  int* __restrict__ tuples,
                                                  int* __restrict__ best) {
  const int s = blockIdx.x, tid = threadIdx.x;
  const int wv = tid >> 6, lane = tid & 63;
  __shared__ float buf[4][256];
  __shared__ float rr[4][32];
  __shared__ float msek[16];
  __shared__ int   primes[16][NSTAGES];
  const int L = it + 2;

  for (int pi = 0; pi < 4; ++pi) {
    const int p = wv * 4 + pi;
    const int b = p >> 2, c = p & 3;
    int tpl[NSTAGES];
    for (int a = 0; a < NSTAGES; ++a) tpl[a] = tuples[(s * BEAM_W + b) * NSTAGES + a];
    tpl[it + 1] = cand[(s * BEAM_W + b) * BEAM_W + c];
    if (lane == 0)
      for (int a = 0; a < NSTAGES; ++a) primes[p][a] = tpl[a];
    for (int d = lane; d < D; d += 64) {
      float q = cb[(size_t)tpl[0] * D + d];
      for (int a = 1; a < L; ++a) q = __fadd_rn(q, cb[(size_t)tpl[a] * D + d]);
      float v = __fsub_rn(x[(size_t)s * D + d], q);
      buf[wv][d] = __fmul_rn(v, v);
    }
    __syncthreads();
    if (lane < 32) {
      float r = buf[wv][lane];
      for (int i = 32; i < 256; i += 32) r = __fadd_rn(r, buf[wv][i + lane]);
      rr[wv][lane] = r;
    }
    __syncthreads();
    if (lane == 0) {
      float w[8];
#pragma unroll
      for (int j = 0; j < 8; ++j)
        w[j] = __fadd_rn(__fadd_rn(__fadd_rn(rr[wv][j], rr[wv][8 + j]), rr[wv][16 + j]),
                         rr[wv][24 + j]);
      float s0 = __fadd_rn(w[0], w[4]);
      float s1 = __fadd_rn(w[1], w[5]);
      float s2 = __fadd_rn(w[2], w[6]);
      float s3 = __fadd_rn(w[3], w[7]);
      float t0 = __fadd_rn(s0, s2);
      float t1 = __fadd_rn(s1, s3);
      float S2 = __fadd_rn(t0, t1);
      msek[p] = __fmul_rn(S2, 0.00390625f);
    }
    __syncthreads();
  }

  if (tid == 0) {
    if (it < NSTAGES - 2) {
      bool taken[16] = {false};
      int  newt[BEAM_W][NSTAGES];
      for (int r = 0; r < BEAM_W; ++r) {
        int bp = -1; float bk = 0.0f;
        for (int p = 0; p < 16; ++p) {
          if (taken[p]) continue;
          if (bp < 0 || msek[p] < bk) { bk = msek[p]; bp = p; }
        }
        taken[bp] = true;
        for (int a = 0; a < NSTAGES; ++a) newt[r][a] = primes[bp][a];
      }
      for (int r = 0; r < BEAM_W; ++r)
        for (int a = 0; a < NSTAGES; ++a) tuples[(s * BEAM_W + r) * NSTAGES + a] = newt[r][a];
    } else {
      int bp = 0; float bk = msek[0];
      for (int p = 1; p < 16; ++p)
        if (msek[p] < bk) { bk = msek[p]; bp = p; }
      for (int a = 0; a < NSTAGES; ++a) best[s * NSTAGES + a] = primes[bp][a];
    }
  }
}

// ---------------- zero the 'used' region of d_out
__global__ void zero_used(float* __restrict__ u) {
  int t = blockIdx.x * 256 + threadIdx.x;
  if (t < SK) u[t] = 0.0f;
}

// ---------------- epilogue: nsvq (or quantized) + used bitmap
__global__ __launch_bounds__(256) void finalize_kernel(const float* __restrict__ x,
                                                       const float* __restrict__ cb,
                                                       const float* __restrict__ rvec,
                                                       const int* __restrict__ best,
                                                       const int* __restrict__ tmode,
                                                       float* __restrict__ out) {
  const int i = blockIdx.x;
  const int t = threadIdx.x;
  __shared__ double s1[256], s2[256];
  const int b0 = best[i * 4 + 0], b1 = best[i * 4 + 1];
  const int b2 = best[i * 4 + 2], b3 = best[i * 4 + 3];
  float q = ((cb[(size_t)b0 * D + t] + cb[(size_t)b1 * D + t]) + cb[(size_t)b2 * D + t]) +
            cb[(size_t)b3 * D + t];
  float xv = x[(size_t)i * D + t];
  float rv = rvec[(size_t)i * D + t];
  float df = xv - q;
  s1[t] = (double)df * (double)df;
  s2[t] = (double)rv * (double)rv;
  __syncthreads();
  for (int off = 128; off; off >>= 1) {
    if (t < off) { s1[t] += s1[t + off]; s2[t] += s2[t + off]; }
    __syncthreads();
  }
  float nh = sqrtf((float)s1[0]);
  float nr = sqrtf((float)s2[0]);
  float ratio = nh / nr + 1e-12f;
  out[(size_t)i * D + t] = (*tmode != 0) ? (xv + ratio * rv) : q;
  if (t < 4) out[(size_t)NB * D + best[i * 4 + t]] = 1.0f;
}

// ----------------------------------------------------------------
extern "C" void kernel_launch(void* const* d_in, const int* in_sizes, int n_in,
                              void* d_out, int out_size, void* d_ws, size_t ws_size,
                              hipStream_t stream) {
  const float* x   = (const float*)d_in[0];
  const float* cb  = (const float*)d_in[1];
  const float* rv  = (const float*)d_in[2];
  const int*   tm  = (const int*)d_in[3];
  float*       out = (float*)d_out;

  const size_t XC_BYTES    = (size_t)NB * SK * sizeof(float);                 // 64 MB
  const size_t G_BYTES     = (size_t)SK * SK * sizeof(float);                 // 64 MB
  const size_t BT_BYTES    = (size_t)D * SK * sizeof(float);                  // 4 MB
  const size_t AT0_BYTES   = (size_t)D * NB * sizeof(float);                  // 4 MB
  const size_t ATL_BYTES   = (size_t)D * NB * BEAM_W * sizeof(float);         // 16 MB (legacy)
  const size_t PKI0_BYTES  = (size_t)NCBLK * NB * BEAM_W * sizeof(u64);       // 2.1 MB
  const size_t PKIL_BYTES  = (size_t)NCBLK * NB * BEAM_W * 4 * sizeof(u64);   // 8.4 MB (legacy)
  const size_t S_BYTES     = (size_t)NB * BEAM_W * sizeof(float);
  const size_t CB2_BYTES   = (size_t)SK * sizeof(float);
  const size_t TUP_BYTES   = (size_t)NB * BEAM_W * NSTAGES * sizeof(int);
  const size_t CAND_BYTES  = (size_t)NB * BEAM_W * BEAM_W * sizeof(int);
  const size_t BEST_BYTES  = (size_t)NB * NSTAGES * sizeof(int);
  const size_t SMALL = S_BYTES + CB2_BYTES + TUP_BYTES + CAND_BYTES + BEST_BYTES;

  const size_t NEW_TOTAL    = XC_BYTES + G_BYTES + BT_BYTES + AT0_BYTES + PKI0_BYTES + SMALL;
  const size_t LEGACY_TOTAL = PKIL_BYTES + BT_BYTES + ATL_BYTES + SMALL;

  if (ws_size >= NEW_TOTAL) {
    // ---- fast path: step-0 GEMM first (R14 order), THEN G pipeline, then key_select
    char* ws = (char*)d_ws;
    float* XC   = (float*)ws;  ws += XC_BYTES;
    float* G    = (float*)ws;  ws += G_BYTES;
    float* cbT  = (float*)ws;  ws += BT_BYTES;
    float* AT   = (float*)ws;  ws += AT0_BYTES;
    u64*   pki  = (u64*)ws;    ws += PKI0_BYTES;
    float* Srow = (float*)ws;  ws += S_BYTES;
    float* cb2  = (float*)ws;  ws += CB2_BYTES;
    int*   tup  = (int*)ws;    ws += TUP_BYTES;
    int*   cand = (int*)ws;    ws += CAND_BYTES;
    int*   best = (int*)ws;

    cb2_pw<<<SK / 256, 256, 0, stream>>>(cb, cb2);
    s0_pw<<<NB / 256, 256, 0, stream>>>(x, Srow);
    transpose_rem<<<dim3(SK / 64, D / 64), 256, 0, stream>>>(cb, cb, tup, 0, 1, SK, cbT);
    transpose_rem<<<dim3(NB / 64, D / 64), 256, 0, stream>>>(x, cb, tup, 0, 1, NB, AT);

    gemm_fused<<<dim3(NCBLK, NB / RB), 256, 0, stream>>>(AT, cbT, Srow, cb2, tup, 0, 1, NB,
                                                         pki, XC);             // step0 + XC
    reduce_top4<<<NB / 256, 256, 0, stream>>>(pki, NB, 1, tup, cand);

    gemm_plain<<<dim3(NCBLK, SK / RB), 256, 0, stream>>>(cbT, cbT, SK, 1, G);  // upper+diag
    mirror_g<<<dim3(SK / 64, SK / 64), 256, 0, stream>>>(G);                   // lower tiles

    for (int it = 0; it < NSTAGES - 1; ++it)
      key_select<<<NB, 256, 0, stream>>>(XC, G, cb2, x, cb, it, tup, best);

    zero_used<<<SK / 256, 256, 0, stream>>>(out + (size_t)NB * D);
    finalize_kernel<<<NB, 256, 0, stream>>>(x, cb, rv, best, tm, out);
    return;
  }

  if (ws_size < LEGACY_TOTAL) return;
  // ---------------- legacy path (R0-proven) ----------------
  char* ws = (char*)d_ws;
  u64*   pki  = (u64*)ws;    ws += PKIL_BYTES;
  float* cbT  = (float*)ws;  ws += BT_BYTES;
  float* AT   = (float*)ws;  ws += ATL_BYTES;
  float* Srow = (float*)ws;  ws += S_BYTES;
  float* cb2  = (float*)ws;  ws += CB2_BYTES;
  int*   tup  = (int*)ws;    ws += TUP_BYTES;
  int*   cand = (int*)ws;    ws += CAND_BYTES;
  int*   best = (int*)ws;

  cb2_pw<<<SK / 256, 256, 0, stream>>>(cb, cb2);
  s0_pw<<<NB / 256, 256, 0, stream>>>(x, Srow);
  transpose_rem<<<dim3(SK / 64, D / 64), 256, 0, stream>>>(cb, cb, tup, 0, 1, SK, cbT);
  transpose_rem<<<dim3(NB / 64, D / 64), 256, 0, stream>>>(x, cb, tup, 0, 1, NB, AT);

  gemm_fused<<<dim3(NCBLK, NB / RB), 256, 0, stream>>>(AT, cbT, Srow, cb2, tup, 0, 1, NB,
                                                       pki, nullptr);
  reduce_top4<<<NB / 256, 256, 0, stream>>>(pki, NB, 1, tup, cand);

  for (int it = 0; it < NSTAGES - 1; ++it) {
    srow_pw<<<(NB * BEAM_W) / 256, 256, 0, stream>>>(x, cb, tup, it, Srow);
    transpose_rem<<<dim3(NB * BEAM_W / 64, D / 64), 256, 0, stream>>>(x, cb, tup, it, 0,
                                                                      NB * BEAM_W, AT);
    gemm_fused<<<dim3(NCBLK, (NB * BEAM_W) / RB), 256, 0, stream>>>(
        AT, cbT, Srow, cb2, tup, it, 0, NB * BEAM_W, pki, nullptr);
    reduce_top4<<<(NB * BEAM_W) / 256, 256, 0, stream>>>(pki, NB * BEAM_W, 0, tup, cand);
    mse_select<<<NB, 256, 0, stream>>>(x, cb, cand, it, tup, best);
  }

  zero_used<<<SK / 256, 256, 0, stream>>>(out + (size_t)NB * D);
  finalize_kernel<<<NB, 256, 0, stream>>>(x, cb, rv, best, tm, out);
}

// Round 19
// 537.426 us; speedup vs baseline: 1.1715x; 1.0752x over previous
//
#include <hip/hip_runtime.h>
#include <math.h>

#define NSTAGES 4
#define NCB     1024
#define SK      4096   // NSTAGES*NCB
#define D       256
#define BEAM_W  4
#define NB      4096   // N samples
#define INFF    __builtin_huge_valf()
#define RB      128    // gemm rows per block
#define CBL     256    // gemm cols per block
#define BK      32     // gemm k-tile (single-buffered; R0-proven — see lessons log)
#define NCBLK   (SK / CBL)   // 16 col-blocks

typedef unsigned long long u64;

// LESSONS LOG (measured, this session):
//   R0: single-buffer BK=32 + tki merge = 476 us/big-gemm. Best GEMM schedule.
//   R1-R6: GEMM micro-scheduling closed (dbuf spills or regresses).
//   R7: remainder GEMMs factorized via M = XC - mf*G. 1705 -> 709 us, PASSED.
//   R8: factorized msek FAILED — msek MUST be the FROZEN D-loop chain. Key-scan
//     partitioning IS exact (top-4 = set function of distinct u64s).
//   R9/R10: fused wave-private key_select PASSED. 709 -> 599 us.
//   R11/R12: step-0 must stay fused in gemm_fused (free); 512-thr split-scan regressed.
//   R13: sym-G + in-kernel Srow PASSED (592); mirror_g before gemm_fused = L2 pollution.
//   R14: reorder fixed gemm_fused (136); 4-sublist scan regressed (+30/step, registers).
//   R15: R14 order + single-list scan = 581. R16: drop XC LDS staging = 575. BEST.
//   R17: fusing 3 key_select launches into one beam_iter REGRESSED. Beam phase is
//     optimal as 3 short 256-thread launches. All beam RESTRUCTURINGS closed.
//   R18: R16 re-confirmed (577.8, within noise of 575.1).
//   R19 (this): skip banned-group scan iterations in key_select (group = i>>2,
//     wave-uniform branch). EXACT: >=1024 finite keys always exist, so INFF entries
//     never reach the top-4; per-lane cover merge unchanged. Cuts scan work+G loads
//     by 25/50/75% for it=0/1/2. Work-reduction, not scheduling.

// ---------------- LLVM-vectorized reduce over 256 f32, VF=8, IC=4 (FROZEN - bit-exact vs ref)
template <typename F>
__device__ __forceinline__ float xw84(F v) {
  float r[32];
#pragma unroll
  for (int l = 0; l < 32; ++l) r[l] = v(l);
  for (int i = 32; i < 256; i += 32)
#pragma unroll
    for (int l = 0; l < 32; ++l) r[l] = __fadd_rn(r[l], v(i + l));
  float w[8];
#pragma unroll
  for (int j = 0; j < 8; ++j)
    w[j] = __fadd_rn(__fadd_rn(__fadd_rn(r[j], r[8 + j]), r[16 + j]), r[24 + j]);
  float s0 = __fadd_rn(w[0], w[4]);
  float s1 = __fadd_rn(w[1], w[5]);
  float s2 = __fadd_rn(w[2], w[6]);
  float s3 = __fadd_rn(w[3], w[7]);
  float t0 = __fadd_rn(s0, s2);
  float t1 = __fadd_rn(s1, s3);
  return __fadd_rn(t0, t1);
}

// ---------------- sorted ascending top-4 insert on packed u64 (keybits<<32 | idx).
// Keys are ~250 (>0) so float order == bit order; u64 order == lex (key, idx). FROZEN ties.
__device__ __forceinline__ void ins4u(u64 v, u64 b[4]) {
  if (v < b[3]) {
    b[3] = v;
    if (b[3] < b[2]) { u64 t = b[2]; b[2] = b[3]; b[3] = t; }
    if (b[2] < b[1]) { u64 t = b[1]; b[1] = b[2]; b[2] = t; }
    if (b[1] < b[0]) { u64 t = b[0]; b[0] = b[1]; b[1] = t; }
  }
}

// 64-bit shuffle-xor via two 32-bit shuffles (HIP-overload-proof)
__device__ __forceinline__ u64 shflx64(u64 v, int m) {
  int lo = __shfl_xor((int)(unsigned)(v & 0xFFFFFFFFULL), m, 64);
  int hi = __shfl_xor((int)(unsigned)(v >> 32), m, 64);
  return ((u64)(unsigned)hi << 32) | (u64)(unsigned)lo;
}

// ---------------- cb2[j] = sum(cb[j]**2)
__global__ __launch_bounds__(256) void cb2_pw(const float* __restrict__ cb,
                                              float* __restrict__ cb2) {
  int row = blockIdx.x * 256 + threadIdx.x;
  if (row >= SK) return;
  const float* c = cb + (size_t)row * D;
  cb2[row] = xw84([&](int d) { float t = c[d]; return __fmul_rn(t, t); });
}

// ---------------- Srow[s] = sum(x[s]**2)
__global__ __launch_bounds__(256) void s0_pw(const float* __restrict__ x,
                                             float* __restrict__ Srow) {
  int row = blockIdx.x * 256 + threadIdx.x;
  if (row >= NB) return;
  const float* xr = x + (size_t)row * D;
  Srow[row] = xw84([&](int d) { float t = xr[d]; return __fmul_rn(t, t); });
}

// ---------------- Srow for remainder rows (legacy path only; FROZEN numerics)
__global__ __launch_bounds__(256) void srow_pw(const float* __restrict__ x,
                                               const float* __restrict__ cb,
                                               const int* __restrict__ tuples,
                                               int it,
                                               float* __restrict__ Srow) {
  int row = blockIdx.x * 256 + threadIdx.x;
  if (row >= NB * BEAM_W) return;
  int s = row >> 2;
  int slot = tuples[row * NSTAGES + it];
  const float* xr = x + (size_t)s * D;
  const float* cr = cb + (size_t)slot * D;
  const float mf = (float)(it + 1);
  Srow[row] = xw84([&](int d) {
    float t = __fsub_rn(xr[d], __fmul_rn(mf, cr[d]));
    return __fmul_rn(t, t);
  });
}

// ---------------- k-major transpose (FROZEN)
__global__ __launch_bounds__(256) void transpose_rem(
    const float* __restrict__ x, const float* __restrict__ cbk,
    const int* __restrict__ tuples, int it, int isStep0, int nrows,
    float* __restrict__ AT) {
  __shared__ float tile[64][65];
  const int t = threadIdx.x;
  const int r0 = blockIdx.x * 64;
  const int d0 = blockIdx.y * 64;
  const float mf = (float)(it + 1);
  {
    int r = r0 + (t & 63);
    int db = (t >> 6) * 16;
    const float* xr;
    const float* cr = nullptr;
    if (isStep0) {
      xr = x + (size_t)r * D;
    } else {
      xr = x + (size_t)(r >> 2) * D;
      cr = cbk + (size_t)tuples[r * NSTAGES + it] * D;
    }
#pragma unroll
    for (int l = 0; l < 4; ++l) {
      float4 v = *(const float4*)&xr[d0 + db + l * 4];
      if (!isStep0) {
        float4 c = *(const float4*)&cr[d0 + db + l * 4];
        v.x = __fsub_rn(v.x, __fmul_rn(mf, c.x));
        v.y = __fsub_rn(v.y, __fmul_rn(mf, c.y));
        v.z = __fsub_rn(v.z, __fmul_rn(mf, c.z));
        v.w = __fsub_rn(v.w, __fmul_rn(mf, c.w));
      }
      tile[t & 63][db + l * 4 + 0] = v.x;
      tile[t & 63][db + l * 4 + 1] = v.y;
      tile[t & 63][db + l * 4 + 2] = v.z;
      tile[t & 63][db + l * 4 + 3] = v.w;
    }
  }
  __syncthreads();
  {
    int dd = t >> 2;
    int rb = (t & 3) * 16;
    float* orow = AT + (size_t)(d0 + dd) * nrows + r0 + rb;
#pragma unroll
    for (int l = 0; l < 4; ++l) {
      float4 v = make_float4(tile[rb + l * 4 + 0][dd], tile[rb + l * 4 + 1][dd],
                             tile[rb + l * 4 + 2][dd], tile[rb + l * 4 + 3][dd]);
      *(float4*)&orow[l * 4] = v;
    }
  }
}

// ---------------- plain GEMM (R0 schedule). sym=1: skip tiles strictly below the
// diagonal (row0 >= col0+CBL) — mirror_g fills them with bit-identical values
// (fl(a*b+c) == fl(b*a+c), identical ascending-k chain).
__global__ __launch_bounds__(256, 2) void gemm_plain(
    const float* __restrict__ AT, const float* __restrict__ BT, int nrows, int sym,
    float* __restrict__ Gout) {
  const int row0 = blockIdx.y * RB;
  const int col0 = blockIdx.x * CBL;
  if (sym && row0 >= col0 + CBL) return;   // block-uniform exit, before any barrier
  __shared__ __align__(16) float AsF[BK * 128];   // 16 KB
  __shared__ __align__(16) float BsF[BK * 256];   // 32 KB
  const int tid  = threadIdx.x;
  const int wv   = tid >> 6;
  const int lane = tid & 63;
  const int tx = tid & 15, ty = tid >> 4;

  const float* aSrc[4];
  const float* bSrc[8];
#pragma unroll
  for (int c = 0; c < 4; ++c) {
    int f = (wv * 4 + c) * 256 + lane * 4;
    aSrc[c] = AT + (size_t)(f >> 7) * nrows + row0 + (f & 127);
  }
#pragma unroll
  for (int c = 0; c < 8; ++c) {
    int f = (wv * 8 + c) * 256 + lane * 4;
    bSrc[c] = BT + (size_t)(f >> 8) * SK + col0 + (f & 255);
  }

  float acc[8][16];
#pragma unroll
  for (int i = 0; i < 8; ++i)
#pragma unroll
    for (int j = 0; j < 16; ++j) acc[i][j] = 0.0f;

  for (int kt = 0; kt < D; kt += BK) {
#pragma unroll
    for (int c = 0; c < 4; ++c)
      __builtin_amdgcn_global_load_lds(
          (const __attribute__((address_space(1))) void*)aSrc[c],
          (__attribute__((address_space(3))) void*)(AsF + (wv * 4 + c) * 256), 16, 0, 0);
#pragma unroll
    for (int c = 0; c < 8; ++c)
      __builtin_amdgcn_global_load_lds(
          (const __attribute__((address_space(1))) void*)bSrc[c],
          (__attribute__((address_space(3))) void*)(BsF + (wv * 8 + c) * 256), 16, 0, 0);
#pragma unroll
    for (int c = 0; c < 4; ++c) aSrc[c] += (size_t)BK * nrows;
#pragma unroll
    for (int c = 0; c < 8; ++c) bSrc[c] += (size_t)BK * SK;
    __syncthreads();

#pragma unroll 8
    for (int k = 0; k < BK; ++k) {   // ascending k only — do not reorder
      float a[8], b[16];
      *(float4*)&a[0]  = *(const float4*)&AsF[k * 128 + ty * 4];
      *(float4*)&a[4]  = *(const float4*)&AsF[k * 128 + 64 + ty * 4];
      *(float4*)&b[0]  = *(const float4*)&BsF[k * 256 + tx * 4];
      *(float4*)&b[4]  = *(const float4*)&BsF[k * 256 + 64 + tx * 4];
      *(float4*)&b[8]  = *(const float4*)&BsF[k * 256 + 128 + tx * 4];
      *(float4*)&b[12] = *(const float4*)&BsF[k * 256 + 192 + tx * 4];
#pragma unroll
      for (int i = 0; i < 8; ++i)
#pragma unroll
        for (int j = 0; j < 16; ++j)
          acc[i][j] = __fmaf_rn(a[i], b[j], acc[i][j]);
    }
    __syncthreads();
  }

#pragma unroll
  for (int i = 0; i < 8; ++i) {
    int lrow = (i & 3) + ((i >> 2) * 64) + ty * 4;
    float* go = Gout + (size_t)(row0 + lrow) * SK + col0;
#pragma unroll
    for (int jj = 0; jj < 4; ++jj) {
      float4 v = make_float4(acc[i][jj * 4 + 0], acc[i][jj * 4 + 1],
                             acc[i][jj * 4 + 2], acc[i][jj * 4 + 3]);
      *(float4*)&go[jj * 64 + tx * 4] = v;
    }
  }
}

// ---------------- mirror the skipped lower tiles of symmetric G: G[i][j] = G[j][i].
__global__ __launch_bounds__(256) void mirror_g(float* __restrict__ G) {
  const int bi = blockIdx.x, bj = blockIdx.y;   // target 64-row / 64-col blocks
  if (((bi >> 1) * RB) < ((bj >> 2) * CBL) + CBL) return;  // target tile was computed
  __shared__ float tile[64][65];
  const int t = threadIdx.x;
  const int rr = t & 63, c0 = (t >> 6) * 16;
  {
    const float* src = G + (size_t)(bj * 64 + rr) * SK + bi * 64 + c0;
#pragma unroll
    for (int l = 0; l < 16; l += 4) {
      float4 v = *(const float4*)&src[l];
      tile[rr][c0 + l + 0] = v.x;
      tile[rr][c0 + l + 1] = v.y;
      tile[rr][c0 + l + 2] = v.z;
      tile[rr][c0 + l + 3] = v.w;
    }
  }
  __syncthreads();
  {
    float* dst = G + (size_t)(bi * 64 + rr) * SK + bj * 64 + c0;
#pragma unroll
    for (int l = 0; l < 16; l += 4) {
      float4 v = make_float4(tile[c0 + l + 0][rr], tile[c0 + l + 1][rr],
                             tile[c0 + l + 2][rr], tile[c0 + l + 3][rr]);
      *(float4*)&dst[l] = v;
    }
  }
}

// ---------------- fused GEMM (R0 schedule) + XC dump + key + top-4 (tki merge).
// R10-proven step-0 path (key/selection comes free with the GEMM epilogue).
__global__ __launch_bounds__(256, 2) void gemm_fused(
    const float* __restrict__ AT, const float* __restrict__ BT,
    const float* __restrict__ Srow, const float* __restrict__ cb2,
    const int* __restrict__ tuples, int it, int isStep0, int nrows,
    u64* __restrict__ pki, float* __restrict__ XCout) {
  __shared__ __align__(16) char smem[66560];
  float* AsF = (float*)smem;
  float* BsF = (float*)(smem + 16384);
  u64*   tki = (u64*)smem;
  const int tid  = threadIdx.x;
  const int wv   = tid >> 6;
  const int lane = tid & 63;
  const int tx = tid & 15, ty = tid >> 4;
  const int row0 = blockIdx.y * RB;
  const int col0 = blockIdx.x * CBL;

  const float* aSrc[4];
  const float* bSrc[8];
#pragma unroll
  for (int c = 0; c < 4; ++c) {
    int f = (wv * 4 + c) * 256 + lane * 4;
    aSrc[c] = AT + (size_t)(f >> 7) * nrows + row0 + (f & 127);
  }
#pragma unroll
  for (int c = 0; c < 8; ++c) {
    int f = (wv * 8 + c) * 256 + lane * 4;
    bSrc[c] = BT + (size_t)(f >> 8) * SK + col0 + (f & 255);
  }

  float acc[8][16];
#pragma unroll
  for (int i = 0; i < 8; ++i)
#pragma unroll
    for (int j = 0; j < 16; ++j) acc[i][j] = 0.0f;

  for (int kt = 0; kt < D; kt += BK) {
#pragma unroll
    for (int c = 0; c < 4; ++c)
      __builtin_amdgcn_global_load_lds(
          (const __attribute__((address_space(1))) void*)aSrc[c],
          (__attribute__((address_space(3))) void*)(AsF + (wv * 4 + c) * 256), 16, 0, 0);
#pragma unroll
    for (int c = 0; c < 8; ++c)
      __builtin_amdgcn_global_load_lds(
          (const __attribute__((address_space(1))) void*)bSrc[c],
          (__attribute__((address_space(3))) void*)(BsF + (wv * 8 + c) * 256), 16, 0, 0);
#pragma unroll
    for (int c = 0; c < 4; ++c) aSrc[c] += (size_t)BK * nrows;
#pragma unroll
    for (int c = 0; c < 8; ++c) bSrc[c] += (size_t)BK * SK;
    __syncthreads();

#pragma unroll 8
    for (int k = 0; k < BK; ++k) {   // ascending k only — do not reorder
      float a[8], b[16];
      *(float4*)&a[0]  = *(const float4*)&AsF[k * 128 + ty * 4];
      *(float4*)&a[4]  = *(const float4*)&AsF[k * 128 + 64 + ty * 4];
      *(float4*)&b[0]  = *(const float4*)&BsF[k * 256 + tx * 4];
      *(float4*)&b[4]  = *(const float4*)&BsF[k * 256 + 64 + tx * 4];
      *(float4*)&b[8]  = *(const float4*)&BsF[k * 256 + 128 + tx * 4];
      *(float4*)&b[12] = *(const float4*)&BsF[k * 256 + 192 + tx * 4];
#pragma unroll
      for (int i = 0; i < 8; ++i)
#pragma unroll
        for (int j = 0; j < 16; ++j)
          acc[i][j] = __fmaf_rn(a[i], b[j], acc[i][j]);
    }
    __syncthreads();
  }

  if (XCout) {
#pragma unroll
    for (int i = 0; i < 8; ++i) {
      int lrow = (i & 3) + ((i >> 2) * 64) + ty * 4;
      float* xo = XCout + (size_t)(row0 + lrow) * SK + col0;
#pragma unroll
      for (int jj = 0; jj < 4; ++jj) {
        float4 v = make_float4(acc[i][jj * 4 + 0], acc[i][jj * 4 + 1],
                               acc[i][jj * 4 + 2], acc[i][jj * 4 + 3]);
        *(float4*)&xo[(jj) * 64 + tx * 4] = v;
      }
    }
  }

#pragma unroll
  for (int i = 0; i < 8; ++i) {
    int lrow = (i & 3) + ((i >> 2) * 64) + ty * 4;
    int grow = row0 + lrow;
    float S = Srow[grow];
    int banned = 0;
    if (!isStep0)
      for (int a = 0; a <= it; ++a) banned |= 1 << (tuples[grow * NSTAGES + a] >> 10);
    u64 b4[4] = {~0ULL, ~0ULL, ~0ULL, ~0ULL};
#pragma unroll
    for (int j = 0; j < 16; ++j) {
      int gcol = col0 + (j & 3) + ((j >> 2) * 64) + tx * 4;
      float key = ((banned >> (gcol >> 10)) & 1)
                      ? INFF
                      : __fadd_rn(__fsub_rn(S, __fmul_rn(2.0f, acc[i][j])), cb2[gcol]);
      ins4u(((u64)__float_as_uint(key) << 32) | (unsigned)gcol, b4);
    }
#pragma unroll
    for (int s = 0; s < 4; ++s) tki[(size_t)lrow * 65 + tx * 4 + s] = b4[s];
  }
  __syncthreads();

  if (tid < RB) {
    u64 b4[4] = {~0ULL, ~0ULL, ~0ULL, ~0ULL};
    for (int t = 0; t < 16; ++t)
#pragma unroll
      for (int s = 0; s < 4; ++s) ins4u(tki[(size_t)tid * 65 + t * 4 + s], b4);
    size_t base = ((size_t)blockIdx.x * nrows + row0 + tid) * 4;
#pragma unroll
    for (int s = 0; s < 4; ++s) pki[base + s] = b4[s];
  }
}

// ---------------- merge 16 per-block top-4 lists per row -> global top-4 (exact lex)
__global__ __launch_bounds__(256) void reduce_top4(
    const u64* __restrict__ pki, int nrows, int isStep0,
    int* __restrict__ tup, int* __restrict__ cand) {
  int r = blockIdx.x * 256 + threadIdx.x;
  if (r >= nrows) return;
  u64 b4[4] = {~0ULL, ~0ULL, ~0ULL, ~0ULL};
  for (int cblk = 0; cblk < NCBLK; ++cblk) {
    size_t base = ((size_t)cblk * nrows + r) * 4;
    ins4u(pki[base + 0], b4);
    ins4u(pki[base + 1], b4);
    ins4u(pki[base + 2], b4);
    ins4u(pki[base + 3], b4);
  }
  if (isStep0) {
#pragma unroll
    for (int s = 0; s < 4; ++s)
      tup[(r * BEAM_W + s) * NSTAGES + 0] = (int)(b4[s] & 0xFFFFFFFFULL);
  } else {
#pragma unroll
    for (int s = 0; s < 4; ++s)
      cand[r * BEAM_W + s] = (int)(b4[s] & 0xFFFFFFFFULL);
  }
}

// ---------------- fused per-step kernel (R16 structure + R19 banned-group skip):
// in-kernel Srow (FROZEN replica) + factorized keys (single-list scan over UNBANNED
// groups only — exact, see lessons log) + butterfly top-4 (exact) + shuffle-based mse
// (FROZEN chain) + select.
__global__ __launch_bounds__(256) void key_select(
    const float* __restrict__ XC, const float* __restrict__ G,
    const float* __restrict__ cb2,
    const float* __restrict__ x, const float* __restrict__ cb,
    int it, int* __restrict__ tuples, int* __restrict__ best) {
  const int s = blockIdx.x;
  const int t = threadIdx.x;
  const int b = t >> 6, l = t & 63;
  __shared__ int   tup_s[4][NSTAGES];
  __shared__ float msek[16];
  __shared__ int   primes[16][NSTAGES];

  if (t < 16) tup_s[t >> 2][t & 3] = tuples[(s * BEAM_W + (t >> 2)) * NSTAGES + (t & 3)];
  __syncthreads();   // barrier 1: tup_s visible to all waves

  const float mf = (float)(it + 1);
  const int slot = tup_s[b][it];
  int banned = 0;
  for (int a = 0; a <= it; ++a) banned |= 1 << (tup_s[b][a] >> 10);

  // ---- in-kernel Srow: FROZEN xw84 replica (R11-R16 validated)
  float S;
  {
    const int ll = l & 31;
    const float* xr = x + (size_t)s * D;
    const float* cr = cb + (size_t)slot * D;
    float tt = __fsub_rn(xr[ll], __fmul_rn(mf, cr[ll]));
    float rl = __fmul_rn(tt, tt);
    for (int i = 32; i < 256; i += 32) {
      float t2 = __fsub_rn(xr[ll + i], __fmul_rn(mf, cr[ll + i]));
      rl = __fadd_rn(rl, __fmul_rn(t2, t2));
    }
    int j = l & 7;
    float rj   = __shfl(rl, j, 64);
    float rj8  = __shfl(rl, j + 8, 64);
    float rj16 = __shfl(rl, j + 16, 64);
    float rj24 = __shfl(rl, j + 24, 64);
    float w = __fadd_rn(__fadd_rn(__fadd_rn(rj, rj8), rj16), rj24);
    float w0 = __shfl(w, 0, 64), w1 = __shfl(w, 1, 64);
    float w2 = __shfl(w, 2, 64), w3 = __shfl(w, 3, 64);
    float w4 = __shfl(w, 4, 64), w5 = __shfl(w, 5, 64);
    float w6 = __shfl(w, 6, 64), w7 = __shfl(w, 7, 64);
    float s0 = __fadd_rn(w0, w4);
    float s1 = __fadd_rn(w1, w5);
    float s2 = __fadd_rn(w2, w6);
    float s3 = __fadd_rn(w3, w7);
    float t0 = __fadd_rn(s0, s2);
    float t1 = __fadd_rn(s1, s3);
    S = __fadd_rn(t0, t1);
  }

  const float* gr = G + (size_t)slot * SK;
  const float* xcr = XC + (size_t)s * SK;

  // ---- key scan over UNBANNED groups only (group = i>>2; wave-uniform skip).
  // EXACT: banned keys are INFF and >=1024 finite keys exist, so the global top-4
  // never contains an INFF entry; cover-merge (per-lane top-4 -> butterfly) unchanged.
  u64 b4[4] = {~0ULL, ~0ULL, ~0ULL, ~0ULL};
#pragma unroll 4
  for (int i = 0; i < 16; ++i) {
    if ((banned >> (i >> 2)) & 1) continue;   // wave-uniform: whole group banned
    int j = (i * 64 + l) * 4;
    float4 g4 = *(const float4*)&gr[j];
    float4 x4 = *(const float4*)&xcr[j];
    float4 c4 = *(const float4*)&cb2[j];
    float m0 = __fsub_rn(x4.x, __fmul_rn(mf, g4.x));
    float m1 = __fsub_rn(x4.y, __fmul_rn(mf, g4.y));
    float m2 = __fsub_rn(x4.z, __fmul_rn(mf, g4.z));
    float m3 = __fsub_rn(x4.w, __fmul_rn(mf, g4.w));
    float k0 = __fadd_rn(__fsub_rn(S, __fmul_rn(2.0f, m0)), c4.x);
    float k1 = __fadd_rn(__fsub_rn(S, __fmul_rn(2.0f, m1)), c4.y);
    float k2 = __fadd_rn(__fsub_rn(S, __fmul_rn(2.0f, m2)), c4.z);
    float k3 = __fadd_rn(__fsub_rn(S, __fmul_rn(2.0f, m3)), c4.w);
    ins4u(((u64)__float_as_uint(k0) << 32) | (unsigned)(j + 0), b4);
    ins4u(((u64)__float_as_uint(k1) << 32) | (unsigned)(j + 1), b4);
    ins4u(((u64)__float_as_uint(k2) << 32) | (unsigned)(j + 2), b4);
    ins4u(((u64)__float_as_uint(k3) << 32) | (unsigned)(j + 3), b4);
  }

  // ---- wave butterfly all-reduce of top-4 (exact lex; lists disjoint at every level)
#pragma unroll
  for (int m = 1; m < 64; m <<= 1) {
    u64 o0 = shflx64(b4[0], m);
    u64 o1 = shflx64(b4[1], m);
    u64 o2 = shflx64(b4[2], m);
    u64 o3 = shflx64(b4[3], m);
    ins4u(o0, b4);
    ins4u(o1, b4);
    ins4u(o2, b4);
    ins4u(o3, b4);
  }

  // ---- mse D-loop, register-resident, shuffle reduce (bit-exact FROZEN chain)
  {
    const int L = it + 2;
#pragma unroll
    for (int pi = 0; pi < 4; ++pi) {
      const int p = b * 4 + pi;
      int tpl[NSTAGES];
      for (int a = 0; a < NSTAGES; ++a) tpl[a] = tup_s[b][a];
      tpl[it + 1] = (int)(b4[pi] & 0xFFFFFFFFULL);
      if (l == 0)
        for (int a = 0; a < NSTAGES; ++a) primes[p][a] = tpl[a];
      float v[4];
#pragma unroll
      for (int m = 0; m < 4; ++m) {
        int d = l + m * 64;
        float q = cb[(size_t)tpl[0] * D + d];
        for (int a = 1; a < L; ++a) q = __fadd_rn(q, cb[(size_t)tpl[a] * D + d]);
        float dv = __fsub_rn(x[(size_t)s * D + d], q);
        v[m] = __fmul_rn(dv, dv);
      }
      float u0 = __shfl_xor(v[0], 32, 64);
      float u1 = __shfl_xor(v[1], 32, 64);
      float u2 = __shfl_xor(v[2], 32, 64);
      float u3 = __shfl_xor(v[3], 32, 64);
      float r0 = __fadd_rn(v[0], u0);
      r0 = __fadd_rn(r0, v[1]);
      r0 = __fadd_rn(r0, u1);
      r0 = __fadd_rn(r0, v[2]);
      r0 = __fadd_rn(r0, u2);
      r0 = __fadd_rn(r0, v[3]);
      r0 = __fadd_rn(r0, u3);
      float a8  = __shfl(r0, l + 8, 64);
      float a16 = __shfl(r0, l + 16, 64);
      float a24 = __shfl(r0, l + 24, 64);
      float w = __fadd_rn(__fadd_rn(__fadd_rn(r0, a8), a16), a24);
      float w0 = __shfl(w, 0, 64), w1 = __shfl(w, 1, 64);
      float w2 = __shfl(w, 2, 64), w3 = __shfl(w, 3, 64);
      float w4 = __shfl(w, 4, 64), w5 = __shfl(w, 5, 64);
      float w6 = __shfl(w, 6, 64), w7 = __shfl(w, 7, 64);
      float s0 = __fadd_rn(w0, w4);
      float s1 = __fadd_rn(w1, w5);
      float s2 = __fadd_rn(w2, w6);
      float s3 = __fadd_rn(w3, w7);
      float t0 = __fadd_rn(s0, s2);
      float t1 = __fadd_rn(s1, s3);
      float S2 = __fadd_rn(t0, t1);
      if (l == 0) msek[p] = __fmul_rn(S2, 0.00390625f);  // /256 exact
    }
  }
  __syncthreads();   // barrier 2: msek + primes visible to t==0

  if (t == 0) {
    if (it < NSTAGES - 2) {
      bool taken[16] = {false};
      int  newt[BEAM_W][NSTAGES];
      for (int rr2 = 0; rr2 < BEAM_W; ++rr2) {
        int bp = -1; float bk = 0.0f;
        for (int p = 0; p < 16; ++p) {
          if (taken[p]) continue;
          if (bp < 0 || msek[p] < bk) { bk = msek[p]; bp = p; }  // strict <: lowest p wins ties
        }
        taken[bp] = true;
        for (int a = 0; a < NSTAGES; ++a) newt[rr2][a] = primes[bp][a];
      }
      for (int rr2 = 0; rr2 < BEAM_W; ++rr2)
        for (int a = 0; a < NSTAGES; ++a)
          tuples[(s * BEAM_W + rr2) * NSTAGES + a] = newt[rr2][a];
    } else {
      int bp = 0; float bk = msek[0];
      for (int p = 1; p < 16; ++p)
        if (msek[p] < bk) { bk = msek[p]; bp = p; }   // argmin: first lowest
      for (int a = 0; a < NSTAGES; ++a) best[s * NSTAGES + a] = primes[bp][a];
    }
  }
}

// ---------------- expand 16 tuples, mse via VF8/IC4 reduce, select (legacy path only)
__global__ __launch_bounds__(256) void mse_select(const float* __restrict__ x,
                                                  const float* __restrict__ cb,
                                                  const int* __restrict__ cand,
                                                  int it,
                                                  int* __restrict__ tuples,
                                                  int* __restrict__ best) {
  const int s = blockIdx.x, tid = threadIdx.x;
  const int wv = tid >> 6, lane = tid & 63;
  __shared__ float buf[4][256];
  __shared__ float rr[4][32];
  __shared__ float msek[16];
  __shared__ int   primes[16][NSTAGES];
  const int L = it + 2;

  for (int pi = 0; pi < 4; ++pi) {
    const int p = wv * 4 + pi;
    const int b = p >> 2, c = p & 3;
    int tpl[NSTAGES];
    for (int a = 0; a < NSTAGES; ++a) tpl[a] = tuples[(s * BEAM_W + b) * NSTAGES + a];
    tpl[it + 1] = cand[(s * BEAM_W + b) * BEAM_W + c];
    if (lane == 0)
      for (int a = 0; a < NSTAGES; ++a) primes[p][a] = tpl[a];
    for (int d = lane; d < D; d += 64) {
      float q = cb[(size_t)tpl[0] * D + d];
      for (int a = 1; a < L; ++a) q = __fadd_rn(q, cb[(size_t)tpl[a] * D + d]);
      float v = __fsub_rn(x[(size_t)s * D + d], q);
      buf[wv][d] = __fmul_rn(v, v);
    }
    __syncthreads();
    if (lane < 32) {
      float r = buf[wv][lane];
      for (int i = 32; i < 256; i += 32) r = __fadd_rn(r, buf[wv][i + lane]);
      rr[wv][lane] = r;
    }
    __syncthreads();
    if (lane == 0) {
      float w[8];
#pragma unroll
      for (int j = 0; j < 8; ++j)
        w[j] = __fadd_rn(__fadd_rn(__fadd_rn(rr[wv][j], rr[wv][8 + j]), rr[wv][16 + j]),
                         rr[wv][24 + j]);
      float s0 = __fadd_rn(w[0], w[4]);
      float s1 = __fadd_rn(w[1], w[5]);
      float s2 = __fadd_rn(w[2], w[6]);
      float s3 = __fadd_rn(w[3], w[7]);
      float t0 = __fadd_rn(s0, s2);
      float t1 = __fadd_rn(s1, s3);
      float S2 = __fadd_rn(t0, t1);
      msek[p] = __fmul_rn(S2, 0.00390625f);
    }
    __syncthreads();
  }

  if (tid == 0) {
    if (it < NSTAGES - 2) {
      bool taken[16] = {false};
      int  newt[BEAM_W][NSTAGES];
      for (int r = 0; r < BEAM_W; ++r) {
        int bp = -1; float bk = 0.0f;
        for (int p = 0; p < 16; ++p) {
          if (taken[p]) continue;
          if (bp < 0 || msek[p] < bk) { bk = msek[p]; bp = p; }
        }
        taken[bp] = true;
        for (int a = 0; a < NSTAGES; ++a) newt[r][a] = primes[bp][a];
      }
      for (int r = 0; r < BEAM_W; ++r)
        for (int a = 0; a < NSTAGES; ++a) tuples[(s * BEAM_W + r) * NSTAGES + a] = newt[r][a];
    } else {
      int bp = 0; float bk = msek[0];
      for (int p = 1; p < 16; ++p)
        if (msek[p] < bk) { bk = msek[p]; bp = p; }
      for (int a = 0; a < NSTAGES; ++a) best[s * NSTAGES + a] = primes[bp][a];
    }
  }
}

// ---------------- zero the 'used' region of d_out
__global__ void zero_used(float* __restrict__ u) {
  int t = blockIdx.x * 256 + threadIdx.x;
  if (t < SK) u[t] = 0.0f;
}

// ---------------- epilogue: nsvq (or quantized) + used bitmap
__global__ __launch_bounds__(256) void finalize_kernel(const float* __restrict__ x,
                                                       const float* __restrict__ cb,
                                                       const float* __restrict__ rvec,
                                                       const int* __restrict__ best,
                                                       const int* __restrict__ tmode,
                                                       float* __restrict__ out) {
  const int i = blockIdx.x;
  const int t = threadIdx.x;
  __shared__ double s1[256], s2[256];
  const int b0 = best[i * 4 + 0], b1 = best[i * 4 + 1];
  const int b2 = best[i * 4 + 2], b3 = best[i * 4 + 3];
  float q = ((cb[(size_t)b0 * D + t] + cb[(size_t)b1 * D + t]) + cb[(size_t)b2 * D + t]) +
            cb[(size_t)b3 * D + t];
  float xv = x[(size_t)i * D + t];
  float rv = rvec[(size_t)i * D + t];
  float df = xv - q;
  s1[t] = (double)df * (double)df;
  s2[t] = (double)rv * (double)rv;
  __syncthreads();
  for (int off = 128; off; off >>= 1) {
    if (t < off) { s1[t] += s1[t + off]; s2[t] += s2[t + off]; }
    __syncthreads();
  }
  float nh = sqrtf((float)s1[0]);
  float nr = sqrtf((float)s2[0]);
  float ratio = nh / nr + 1e-12f;
  out[(size_t)i * D + t] = (*tmode != 0) ? (xv + ratio * rv) : q;
  if (t < 4) out[(size_t)NB * D + best[i * 4 + t]] = 1.0f;
}

// ----------------------------------------------------------------
extern "C" void kernel_launch(void* const* d_in, const int* in_sizes, int n_in,
                              void* d_out, int out_size, void* d_ws, size_t ws_size,
                              hipStream_t stream) {
  const float* x   = (const float*)d_in[0];
  const float* cb  = (const float*)d_in[1];
  const float* rv  = (const float*)d_in[2];
  const int*   tm  = (const int*)d_in[3];
  float*       out = (float*)d_out;

  const size_t XC_BYTES    = (size_t)NB * SK * sizeof(float);                 // 64 MB
  const size_t G_BYTES     = (size_t)SK * SK * sizeof(float);                 // 64 MB
  const size_t BT_BYTES    = (size_t)D * SK * sizeof(float);                  // 4 MB
  const size_t AT0_BYTES   = (size_t)D * NB * sizeof(float);                  // 4 MB
  const size_t ATL_BYTES   = (size_t)D * NB * BEAM_W * sizeof(float);         // 16 MB (legacy)
  const size_t PKI0_BYTES  = (size_t)NCBLK * NB * BEAM_W * sizeof(u64);       // 2.1 MB
  const size_t PKIL_BYTES  = (size_t)NCBLK * NB * BEAM_W * 4 * sizeof(u64);   // 8.4 MB (legacy)
  const size_t S_BYTES     = (size_t)NB * BEAM_W * sizeof(float);
  const size_t CB2_BYTES   = (size_t)SK * sizeof(float);
  const size_t TUP_BYTES   = (size_t)NB * BEAM_W * NSTAGES * sizeof(int);
  const size_t CAND_BYTES  = (size_t)NB * BEAM_W * BEAM_W * sizeof(int);
  const size_t BEST_BYTES  = (size_t)NB * NSTAGES * sizeof(int);
  const size_t SMALL = S_BYTES + CB2_BYTES + TUP_BYTES + CAND_BYTES + BEST_BYTES;

  const size_t NEW_TOTAL    = XC_BYTES + G_BYTES + BT_BYTES + AT0_BYTES + PKI0_BYTES + SMALL;
  const size_t LEGACY_TOTAL = PKIL_BYTES + BT_BYTES + ATL_BYTES + SMALL;

  if (ws_size >= NEW_TOTAL) {
    // ---- fast path: step-0 GEMM first (R14 order), THEN G pipeline, then key_select
    char* ws = (char*)d_ws;
    float* XC   = (float*)ws;  ws += XC_BYTES;
    float* G    = (float*)ws;  ws += G_BYTES;
    float* cbT  = (float*)ws;  ws += BT_BYTES;
    float* AT   = (float*)ws;  ws += AT0_BYTES;
    u64*   pki  = (u64*)ws;    ws += PKI0_BYTES;
    float* Srow = (float*)ws;  ws += S_BYTES;
    float* cb2  = (float*)ws;  ws += CB2_BYTES;
    int*   tup  = (int*)ws;    ws += TUP_BYTES;
    int*   cand = (int*)ws;    ws += CAND_BYTES;
    int*   best = (int*)ws;

    cb2_pw<<<SK / 256, 256, 0, stream>>>(cb, cb2);
    s0_pw<<<NB / 256, 256, 0, stream>>>(x, Srow);
    transpose_rem<<<dim3(SK / 64, D / 64), 256, 0, stream>>>(cb, cb, tup, 0, 1, SK, cbT);
    transpose_rem<<<dim3(NB / 64, D / 64), 256, 0, stream>>>(x, cb, tup, 0, 1, NB, AT);

    gemm_fused<<<dim3(NCBLK, NB / RB), 256, 0, stream>>>(AT, cbT, Srow, cb2, tup, 0, 1, NB,
                                                         pki, XC);             // step0 + XC
    reduce_top4<<<NB / 256, 256, 0, stream>>>(pki, NB, 1, tup, cand);

    gemm_plain<<<dim3(NCBLK, SK / RB), 256, 0, stream>>>(cbT, cbT, SK, 1, G);  // upper+diag
    mirror_g<<<dim3(SK / 64, SK / 64), 256, 0, stream>>>(G);                   // lower tiles

    for (int it = 0; it < NSTAGES - 1; ++it)
      key_select<<<NB, 256, 0, stream>>>(XC, G, cb2, x, cb, it, tup, best);

    zero_used<<<SK / 256, 256, 0, stream>>>(out + (size_t)NB * D);
    finalize_kernel<<<NB, 256, 0, stream>>>(x, cb, rv, best, tm, out);
    return;
  }

  if (ws_size < LEGACY_TOTAL) return;
  // ---------------- legacy path (R0-proven) ----------------
  char* ws = (char*)d_ws;
  u64*   pki  = (u64*)ws;    ws += PKIL_BYTES;
  float* cbT  = (float*)ws;  ws += BT_BYTES;
  float* AT   = (float*)ws;  ws += ATL_BYTES;
  float* Srow = (float*)ws;  ws += S_BYTES;
  float* cb2  = (float*)ws;  ws += CB2_BYTES;
  int*   tup  = (int*)ws;    ws += TUP_BYTES;
  int*   cand = (int*)ws;    ws += CAND_BYTES;
  int*   best = (int*)ws;

  cb2_pw<<<SK / 256, 256, 0, stream>>>(cb, cb2);
  s0_pw<<<NB / 256, 256, 0, stream>>>(x, Srow);
  transpose_rem<<<dim3(SK / 64, D / 64), 256, 0, stream>>>(cb, cb, tup, 0, 1, SK, cbT);
  transpose_rem<<<dim3(NB / 64, D / 64), 256, 0, stream>>>(x, cb, tup, 0, 1, NB, AT);

  gemm_fused<<<dim3(NCBLK, NB / RB), 256, 0, stream>>>(AT, cbT, Srow, cb2, tup, 0, 1, NB,
                                                       pki, nullptr);
  reduce_top4<<<NB / 256, 256, 0, stream>>>(pki, NB, 1, tup, cand);

  for (int it = 0; it < NSTAGES - 1; ++it) {
    srow_pw<<<(NB * BEAM_W) / 256, 256, 0, stream>>>(x, cb, tup, it, Srow);
    transpose_rem<<<dim3(NB * BEAM_W / 64, D / 64), 256, 0, stream>>>(x, cb, tup, it, 0,
                                                                      NB * BEAM_W, AT);
    gemm_fused<<<dim3(NCBLK, (NB * BEAM_W) / RB), 256, 0, stream>>>(
        AT, cbT, Srow, cb2, tup, it, 0, NB * BEAM_W, pki, nullptr);
    reduce_top4<<<(NB * BEAM_W) / 256, 256, 0, stream>>>(pki, NB * BEAM_W, 0, tup, cand);
    mse_select<<<NB, 256, 0, stream>>>(x, cb, cand, it, tup, best);
  }

  zero_used<<<SK / 256, 256, 0, stream>>>(out + (size_t)NB * D);
  finalize_kernel<<<NB, 256, 0, stream>>>(x, cb, rv, best, tm, out);
}

// Round 20
// 496.142 us; speedup vs baseline: 1.2690x; 1.0832x over previous
//
#include <hip/hip_runtime.h>
#include <math.h>

#define NSTAGES 4
#define NCB     1024
#define SK      4096   // NSTAGES*NCB
#define D       256
#define BEAM_W  4
#define NB      4096   // N samples
#define INFF    __builtin_huge_valf()
#define RB      128    // gemm rows per block
#define CBL     256    // gemm cols per block
#define BK      32     // gemm k-tile (single-buffered; R0-proven — see lessons log)
#define NCBLK   (SK / CBL)   // 16 col-blocks

typedef unsigned long long u64;

// LESSONS LOG (measured, this session):
//   R0: single-buffer BK=32 + tki merge = 476 us/big-gemm. Best GEMM schedule.
//   R1-R6: GEMM micro-scheduling closed (dbuf spills or regresses).
//   R7: remainder GEMMs factorized via M = XC - mf*G. 1705 -> 709 us, PASSED.
//   R8: factorized msek FAILED — msek MUST be the FROZEN D-loop chain. Key-scan
//     partitioning IS exact (top-4 = set function of distinct u64s).
//   R9/R10: fused wave-private key_select PASSED. 709 -> 599 us.
//   R11/R12: step-0 must stay fused in gemm_fused (free); 512-thr split-scan regressed.
//   R13: sym-G + in-kernel Srow PASSED (592); mirror_g before gemm_fused = L2 pollution.
//   R14: reorder fixed gemm_fused (136); 4-sublist scan regressed (+30/step, registers).
//   R15: R14 order + single-list scan = 581. R16: drop XC LDS staging = 575.
//   R17: fusing key_select launches regressed. All beam RESTRUCTURINGS closed.
//   R18: R16 re-confirmed (577.8). R19: banned-group skip in scan (EXACT) = 537. BEST.
//   R20 (this): per-beam mse prefix hoist — the 4 candidates of a beam share tuple
//     prefix tpl[0..it]; the FROZEN left-fold adds the candidate row LAST, so
//     pre = fold(cb[tpl[0..it]]) once per beam + one final add per candidate is
//     BIT-IDENTICAL. Cuts mse row-loads 32/48/64 -> 20/24/28 per sample/step.

// ---------------- LLVM-vectorized reduce over 256 f32, VF=8, IC=4 (FROZEN - bit-exact vs ref)
template <typename F>
__device__ __forceinline__ float xw84(F v) {
  float r[32];
#pragma unroll
  for (int l = 0; l < 32; ++l) r[l] = v(l);
  for (int i = 32; i < 256; i += 32)
#pragma unroll
    for (int l = 0; l < 32; ++l) r[l] = __fadd_rn(r[l], v(i + l));
  float w[8];
#pragma unroll
  for (int j = 0; j < 8; ++j)
    w[j] = __fadd_rn(__fadd_rn(__fadd_rn(r[j], r[8 + j]), r[16 + j]), r[24 + j]);
  float s0 = __fadd_rn(w[0], w[4]);
  float s1 = __fadd_rn(w[1], w[5]);
  float s2 = __fadd_rn(w[2], w[6]);
  float s3 = __fadd_rn(w[3], w[7]);
  float t0 = __fadd_rn(s0, s2);
  float t1 = __fadd_rn(s1, s3);
  return __fadd_rn(t0, t1);
}

// ---------------- sorted ascending top-4 insert on packed u64 (keybits<<32 | idx).
// Keys are ~250 (>0) so float order == bit order; u64 order == lex (key, idx). FROZEN ties.
__device__ __forceinline__ void ins4u(u64 v, u64 b[4]) {
  if (v < b[3]) {
    b[3] = v;
    if (b[3] < b[2]) { u64 t = b[2]; b[2] = b[3]; b[3] = t; }
    if (b[2] < b[1]) { u64 t = b[1]; b[1] = b[2]; b[2] = t; }
    if (b[1] < b[0]) { u64 t = b[0]; b[0] = b[1]; b[1] = t; }
  }
}

// 64-bit shuffle-xor via two 32-bit shuffles (HIP-overload-proof)
__device__ __forceinline__ u64 shflx64(u64 v, int m) {
  int lo = __shfl_xor((int)(unsigned)(v & 0xFFFFFFFFULL), m, 64);
  int hi = __shfl_xor((int)(unsigned)(v >> 32), m, 64);
  return ((u64)(unsigned)hi << 32) | (u64)(unsigned)lo;
}

// ---------------- cb2[j] = sum(cb[j]**2)
__global__ __launch_bounds__(256) void cb2_pw(const float* __restrict__ cb,
                                              float* __restrict__ cb2) {
  int row = blockIdx.x * 256 + threadIdx.x;
  if (row >= SK) return;
  const float* c = cb + (size_t)row * D;
  cb2[row] = xw84([&](int d) { float t = c[d]; return __fmul_rn(t, t); });
}

// ---------------- Srow[s] = sum(x[s]**2)
__global__ __launch_bounds__(256) void s0_pw(const float* __restrict__ x,
                                             float* __restrict__ Srow) {
  int row = blockIdx.x * 256 + threadIdx.x;
  if (row >= NB) return;
  const float* xr = x + (size_t)row * D;
  Srow[row] = xw84([&](int d) { float t = xr[d]; return __fmul_rn(t, t); });
}

// ---------------- Srow for remainder rows (legacy path only; FROZEN numerics)
__global__ __launch_bounds__(256) void srow_pw(const float* __restrict__ x,
                                               const float* __restrict__ cb,
                                               const int* __restrict__ tuples,
                                               int it,
                                               float* __restrict__ Srow) {
  int row = blockIdx.x * 256 + threadIdx.x;
  if (row >= NB * BEAM_W) return;
  int s = row >> 2;
  int slot = tuples[row * NSTAGES + it];
  const float* xr = x + (size_t)s * D;
  const float* cr = cb + (size_t)slot * D;
  const float mf = (float)(it + 1);
  Srow[row] = xw84([&](int d) {
    float t = __fsub_rn(xr[d], __fmul_rn(mf, cr[d]));
    return __fmul_rn(t, t);
  });
}

// ---------------- k-major transpose (FROZEN)
__global__ __launch_bounds__(256) void transpose_rem(
    const float* __restrict__ x, const float* __restrict__ cbk,
    const int* __restrict__ tuples, int it, int isStep0, int nrows,
    float* __restrict__ AT) {
  __shared__ float tile[64][65];
  const int t = threadIdx.x;
  const int r0 = blockIdx.x * 64;
  const int d0 = blockIdx.y * 64;
  const float mf = (float)(it + 1);
  {
    int r = r0 + (t & 63);
    int db = (t >> 6) * 16;
    const float* xr;
    const float* cr = nullptr;
    if (isStep0) {
      xr = x + (size_t)r * D;
    } else {
      xr = x + (size_t)(r >> 2) * D;
      cr = cbk + (size_t)tuples[r * NSTAGES + it] * D;
    }
#pragma unroll
    for (int l = 0; l < 4; ++l) {
      float4 v = *(const float4*)&xr[d0 + db + l * 4];
      if (!isStep0) {
        float4 c = *(const float4*)&cr[d0 + db + l * 4];
        v.x = __fsub_rn(v.x, __fmul_rn(mf, c.x));
        v.y = __fsub_rn(v.y, __fmul_rn(mf, c.y));
        v.z = __fsub_rn(v.z, __fmul_rn(mf, c.z));
        v.w = __fsub_rn(v.w, __fmul_rn(mf, c.w));
      }
      tile[t & 63][db + l * 4 + 0] = v.x;
      tile[t & 63][db + l * 4 + 1] = v.y;
      tile[t & 63][db + l * 4 + 2] = v.z;
      tile[t & 63][db + l * 4 + 3] = v.w;
    }
  }
  __syncthreads();
  {
    int dd = t >> 2;
    int rb = (t & 3) * 16;
    float* orow = AT + (size_t)(d0 + dd) * nrows + r0 + rb;
#pragma unroll
    for (int l = 0; l < 4; ++l) {
      float4 v = make_float4(tile[rb + l * 4 + 0][dd], tile[rb + l * 4 + 1][dd],
                             tile[rb + l * 4 + 2][dd], tile[rb + l * 4 + 3][dd]);
      *(float4*)&orow[l * 4] = v;
    }
  }
}

// ---------------- plain GEMM (R0 schedule). sym=1: skip tiles strictly below the
// diagonal (row0 >= col0+CBL) — mirror_g fills them with bit-identical values
// (fl(a*b+c) == fl(b*a+c), identical ascending-k chain).
__global__ __launch_bounds__(256, 2) void gemm_plain(
    const float* __restrict__ AT, const float* __restrict__ BT, int nrows, int sym,
    float* __restrict__ Gout) {
  const int row0 = blockIdx.y * RB;
  const int col0 = blockIdx.x * CBL;
  if (sym && row0 >= col0 + CBL) return;   // block-uniform exit, before any barrier
  __shared__ __align__(16) float AsF[BK * 128];   // 16 KB
  __shared__ __align__(16) float BsF[BK * 256];   // 32 KB
  const int tid  = threadIdx.x;
  const int wv   = tid >> 6;
  const int lane = tid & 63;
  const int tx = tid & 15, ty = tid >> 4;

  const float* aSrc[4];
  const float* bSrc[8];
#pragma unroll
  for (int c = 0; c < 4; ++c) {
    int f = (wv * 4 + c) * 256 + lane * 4;
    aSrc[c] = AT + (size_t)(f >> 7) * nrows + row0 + (f & 127);
  }
#pragma unroll
  for (int c = 0; c < 8; ++c) {
    int f = (wv * 8 + c) * 256 + lane * 4;
    bSrc[c] = BT + (size_t)(f >> 8) * SK + col0 + (f & 255);
  }

  float acc[8][16];
#pragma unroll
  for (int i = 0; i < 8; ++i)
#pragma unroll
    for (int j = 0; j < 16; ++j) acc[i][j] = 0.0f;

  for (int kt = 0; kt < D; kt += BK) {
#pragma unroll
    for (int c = 0; c < 4; ++c)
      __builtin_amdgcn_global_load_lds(
          (const __attribute__((address_space(1))) void*)aSrc[c],
          (__attribute__((address_space(3))) void*)(AsF + (wv * 4 + c) * 256), 16, 0, 0);
#pragma unroll
    for (int c = 0; c < 8; ++c)
      __builtin_amdgcn_global_load_lds(
          (const __attribute__((address_space(1))) void*)bSrc[c],
          (__attribute__((address_space(3))) void*)(BsF + (wv * 8 + c) * 256), 16, 0, 0);
#pragma unroll
    for (int c = 0; c < 4; ++c) aSrc[c] += (size_t)BK * nrows;
#pragma unroll
    for (int c = 0; c < 8; ++c) bSrc[c] += (size_t)BK * SK;
    __syncthreads();

#pragma unroll 8
    for (int k = 0; k < BK; ++k) {   // ascending k only — do not reorder
      float a[8], b[16];
      *(float4*)&a[0]  = *(const float4*)&AsF[k * 128 + ty * 4];
      *(float4*)&a[4]  = *(const float4*)&AsF[k * 128 + 64 + ty * 4];
      *(float4*)&b[0]  = *(const float4*)&BsF[k * 256 + tx * 4];
      *(float4*)&b[4]  = *(const float4*)&BsF[k * 256 + 64 + tx * 4];
      *(float4*)&b[8]  = *(const float4*)&BsF[k * 256 + 128 + tx * 4];
      *(float4*)&b[12] = *(const float4*)&BsF[k * 256 + 192 + tx * 4];
#pragma unroll
      for (int i = 0; i < 8; ++i)
#pragma unroll
        for (int j = 0; j < 16; ++j)
          acc[i][j] = __fmaf_rn(a[i], b[j], acc[i][j]);
    }
    __syncthreads();
  }

#pragma unroll
  for (int i = 0; i < 8; ++i) {
    int lrow = (i & 3) + ((i >> 2) * 64) + ty * 4;
    float* go = Gout + (size_t)(row0 + lrow) * SK + col0;
#pragma unroll
    for (int jj = 0; jj < 4; ++jj) {
      float4 v = make_float4(acc[i][jj * 4 + 0], acc[i][jj * 4 + 1],
                             acc[i][jj * 4 + 2], acc[i][jj * 4 + 3]);
      *(float4*)&go[jj * 64 + tx * 4] = v;
    }
  }
}

// ---------------- mirror the skipped lower tiles of symmetric G: G[i][j] = G[j][i].
__global__ __launch_bounds__(256) void mirror_g(float* __restrict__ G) {
  const int bi = blockIdx.x, bj = blockIdx.y;   // target 64-row / 64-col blocks
  if (((bi >> 1) * RB) < ((bj >> 2) * CBL) + CBL) return;  // target tile was computed
  __shared__ float tile[64][65];
  const int t = threadIdx.x;
  const int rr = t & 63, c0 = (t >> 6) * 16;
  {
    const float* src = G + (size_t)(bj * 64 + rr) * SK + bi * 64 + c0;
#pragma unroll
    for (int l = 0; l < 16; l += 4) {
      float4 v = *(const float4*)&src[l];
      tile[rr][c0 + l + 0] = v.x;
      tile[rr][c0 + l + 1] = v.y;
      tile[rr][c0 + l + 2] = v.z;
      tile[rr][c0 + l + 3] = v.w;
    }
  }
  __syncthreads();
  {
    float* dst = G + (size_t)(bi * 64 + rr) * SK + bj * 64 + c0;
#pragma unroll
    for (int l = 0; l < 16; l += 4) {
      float4 v = make_float4(tile[c0 + l + 0][rr], tile[c0 + l + 1][rr],
                             tile[c0 + l + 2][rr], tile[c0 + l + 3][rr]);
      *(float4*)&dst[l] = v;
    }
  }
}

// ---------------- fused GEMM (R0 schedule) + XC dump + key + top-4 (tki merge).
// R10-proven step-0 path (key/selection comes free with the GEMM epilogue).
__global__ __launch_bounds__(256, 2) void gemm_fused(
    const float* __restrict__ AT, const float* __restrict__ BT,
    const float* __restrict__ Srow, const float* __restrict__ cb2,
    const int* __restrict__ tuples, int it, int isStep0, int nrows,
    u64* __restrict__ pki, float* __restrict__ XCout) {
  __shared__ __align__(16) char smem[66560];
  float* AsF = (float*)smem;
  float* BsF = (float*)(smem + 16384);
  u64*   tki = (u64*)smem;
  const int tid  = threadIdx.x;
  const int wv   = tid >> 6;
  const int lane = tid & 63;
  const int tx = tid & 15, ty = tid >> 4;
  const int row0 = blockIdx.y * RB;
  const int col0 = blockIdx.x * CBL;

  const float* aSrc[4];
  const float* bSrc[8];
#pragma unroll
  for (int c = 0; c < 4; ++c) {
    int f = (wv * 4 + c) * 256 + lane * 4;
    aSrc[c] = AT + (size_t)(f >> 7) * nrows + row0 + (f & 127);
  }
#pragma unroll
  for (int c = 0; c < 8; ++c) {
    int f = (wv * 8 + c) * 256 + lane * 4;
    bSrc[c] = BT + (size_t)(f >> 8) * SK + col0 + (f & 255);
  }

  float acc[8][16];
#pragma unroll
  for (int i = 0; i < 8; ++i)
#pragma unroll
    for (int j = 0; j < 16; ++j) acc[i][j] = 0.0f;

  for (int kt = 0; kt < D; kt += BK) {
#pragma unroll
    for (int c = 0; c < 4; ++c)
      __builtin_amdgcn_global_load_lds(
          (const __attribute__((address_space(1))) void*)aSrc[c],
          (__attribute__((address_space(3))) void*)(AsF + (wv * 4 + c) * 256), 16, 0, 0);
#pragma unroll
    for (int c = 0; c < 8; ++c)
      __builtin_amdgcn_global_load_lds(
          (const __attribute__((address_space(1))) void*)bSrc[c],
          (__attribute__((address_space(3))) void*)(BsF + (wv * 8 + c) * 256), 16, 0, 0);
#pragma unroll
    for (int c = 0; c < 4; ++c) aSrc[c] += (size_t)BK * nrows;
#pragma unroll
    for (int c = 0; c < 8; ++c) bSrc[c] += (size_t)BK * SK;
    __syncthreads();

#pragma unroll 8
    for (int k = 0; k < BK; ++k) {   // ascending k only — do not reorder
      float a[8], b[16];
      *(float4*)&a[0]  = *(const float4*)&AsF[k * 128 + ty * 4];
      *(float4*)&a[4]  = *(const float4*)&AsF[k * 128 + 64 + ty * 4];
      *(float4*)&b[0]  = *(const float4*)&BsF[k * 256 + tx * 4];
      *(float4*)&b[4]  = *(const float4*)&BsF[k * 256 + 64 + tx * 4];
      *(float4*)&b[8]  = *(const float4*)&BsF[k * 256 + 128 + tx * 4];
      *(float4*)&b[12] = *(const float4*)&BsF[k * 256 + 192 + tx * 4];
#pragma unroll
      for (int i = 0; i < 8; ++i)
#pragma unroll
        for (int j = 0; j < 16; ++j)
          acc[i][j] = __fmaf_rn(a[i], b[j], acc[i][j]);
    }
    __syncthreads();
  }

  if (XCout) {
#pragma unroll
    for (int i = 0; i < 8; ++i) {
      int lrow = (i & 3) + ((i >> 2) * 64) + ty * 4;
      float* xo = XCout + (size_t)(row0 + lrow) * SK + col0;
#pragma unroll
      for (int jj = 0; jj < 4; ++jj) {
        float4 v = make_float4(acc[i][jj * 4 + 0], acc[i][jj * 4 + 1],
                               acc[i][jj * 4 + 2], acc[i][jj * 4 + 3]);
        *(float4*)&xo[(jj) * 64 + tx * 4] = v;
      }
    }
  }

#pragma unroll
  for (int i = 0; i < 8; ++i) {
    int lrow = (i & 3) + ((i >> 2) * 64) + ty * 4;
    int grow = row0 + lrow;
    float S = Srow[grow];
    int banned = 0;
    if (!isStep0)
      for (int a = 0; a <= it; ++a) banned |= 1 << (tuples[grow * NSTAGES + a] >> 10);
    u64 b4[4] = {~0ULL, ~0ULL, ~0ULL, ~0ULL};
#pragma unroll
    for (int j = 0; j < 16; ++j) {
      int gcol = col0 + (j & 3) + ((j >> 2) * 64) + tx * 4;
      float key = ((banned >> (gcol >> 10)) & 1)
                      ? INFF
                      : __fadd_rn(__fsub_rn(S, __fmul_rn(2.0f, acc[i][j])), cb2[gcol]);
      ins4u(((u64)__float_as_uint(key) << 32) | (unsigned)gcol, b4);
    }
#pragma unroll
    for (int s = 0; s < 4; ++s) tki[(size_t)lrow * 65 + tx * 4 + s] = b4[s];
  }
  __syncthreads();

  if (tid < RB) {
    u64 b4[4] = {~0ULL, ~0ULL, ~0ULL, ~0ULL};
    for (int t = 0; t < 16; ++t)
#pragma unroll
      for (int s = 0; s < 4; ++s) ins4u(tki[(size_t)tid * 65 + t * 4 + s], b4);
    size_t base = ((size_t)blockIdx.x * nrows + row0 + tid) * 4;
#pragma unroll
    for (int s = 0; s < 4; ++s) pki[base + s] = b4[s];
  }
}

// ---------------- merge 16 per-block top-4 lists per row -> global top-4 (exact lex)
__global__ __launch_bounds__(256) void reduce_top4(
    const u64* __restrict__ pki, int nrows, int isStep0,
    int* __restrict__ tup, int* __restrict__ cand) {
  int r = blockIdx.x * 256 + threadIdx.x;
  if (r >= nrows) return;
  u64 b4[4] = {~0ULL, ~0ULL, ~0ULL, ~0ULL};
  for (int cblk = 0; cblk < NCBLK; ++cblk) {
    size_t base = ((size_t)cblk * nrows + r) * 4;
    ins4u(pki[base + 0], b4);
    ins4u(pki[base + 1], b4);
    ins4u(pki[base + 2], b4);
    ins4u(pki[base + 3], b4);
  }
  if (isStep0) {
#pragma unroll
    for (int s = 0; s < 4; ++s)
      tup[(r * BEAM_W + s) * NSTAGES + 0] = (int)(b4[s] & 0xFFFFFFFFULL);
  } else {
#pragma unroll
    for (int s = 0; s < 4; ++s)
      cand[r * BEAM_W + s] = (int)(b4[s] & 0xFFFFFFFFULL);
  }
}

// ---------------- fused per-step kernel (R19 structure + R20 mse prefix hoist):
// in-kernel Srow (FROZEN replica) + factorized keys (scan over UNBANNED groups only —
// exact) + butterfly top-4 (exact) + shuffle-based mse with per-beam prefix fold
// (BIT-IDENTICAL: candidate row is the last chain element) + select.
__global__ __launch_bounds__(256) void key_select(
    const float* __restrict__ XC, const float* __restrict__ G,
    const float* __restrict__ cb2,
    const float* __restrict__ x, const float* __restrict__ cb,
    int it, int* __restrict__ tuples, int* __restrict__ best) {
  const int s = blockIdx.x;
  const int t = threadIdx.x;
  const int b = t >> 6, l = t & 63;
  __shared__ int   tup_s[4][NSTAGES];
  __shared__ float msek[16];
  __shared__ int   primes[16][NSTAGES];

  if (t < 16) tup_s[t >> 2][t & 3] = tuples[(s * BEAM_W + (t >> 2)) * NSTAGES + (t & 3)];
  __syncthreads();   // barrier 1: tup_s visible to all waves

  const float mf = (float)(it + 1);
  const int slot = tup_s[b][it];
  int banned = 0;
  for (int a = 0; a <= it; ++a) banned |= 1 << (tup_s[b][a] >> 10);

  // ---- in-kernel Srow: FROZEN xw84 replica (R11-R19 validated)
  float S;
  {
    const int ll = l & 31;
    const float* xr = x + (size_t)s * D;
    const float* cr = cb + (size_t)slot * D;
    float tt = __fsub_rn(xr[ll], __fmul_rn(mf, cr[ll]));
    float rl = __fmul_rn(tt, tt);
    for (int i = 32; i < 256; i += 32) {
      float t2 = __fsub_rn(xr[ll + i], __fmul_rn(mf, cr[ll + i]));
      rl = __fadd_rn(rl, __fmul_rn(t2, t2));
    }
    int j = l & 7;
    float rj   = __shfl(rl, j, 64);
    float rj8  = __shfl(rl, j + 8, 64);
    float rj16 = __shfl(rl, j + 16, 64);
    float rj24 = __shfl(rl, j + 24, 64);
    float w = __fadd_rn(__fadd_rn(__fadd_rn(rj, rj8), rj16), rj24);
    float w0 = __shfl(w, 0, 64), w1 = __shfl(w, 1, 64);
    float w2 = __shfl(w, 2, 64), w3 = __shfl(w, 3, 64);
    float w4 = __shfl(w, 4, 64), w5 = __shfl(w, 5, 64);
    float w6 = __shfl(w, 6, 64), w7 = __shfl(w, 7, 64);
    float s0 = __fadd_rn(w0, w4);
    float s1 = __fadd_rn(w1, w5);
    float s2 = __fadd_rn(w2, w6);
    float s3 = __fadd_rn(w3, w7);
    float t0 = __fadd_rn(s0, s2);
    float t1 = __fadd_rn(s1, s3);
    S = __fadd_rn(t0, t1);
  }

  const float* gr = G + (size_t)slot * SK;
  const float* xcr = XC + (size_t)s * SK;

  // ---- key scan over UNBANNED groups only (group = i>>2; wave-uniform skip). EXACT.
  u64 b4[4] = {~0ULL, ~0ULL, ~0ULL, ~0ULL};
#pragma unroll 4
  for (int i = 0; i < 16; ++i) {
    if ((banned >> (i >> 2)) & 1) continue;   // wave-uniform: whole group banned
    int j = (i * 64 + l) * 4;
    float4 g4 = *(const float4*)&gr[j];
    float4 x4 = *(const float4*)&xcr[j];
    float4 c4 = *(const float4*)&cb2[j];
    float m0 = __fsub_rn(x4.x, __fmul_rn(mf, g4.x));
    float m1 = __fsub_rn(x4.y, __fmul_rn(mf, g4.y));
    float m2 = __fsub_rn(x4.z, __fmul_rn(mf, g4.z));
    float m3 = __fsub_rn(x4.w, __fmul_rn(mf, g4.w));
    float k0 = __fadd_rn(__fsub_rn(S, __fmul_rn(2.0f, m0)), c4.x);
    float k1 = __fadd_rn(__fsub_rn(S, __fmul_rn(2.0f, m1)), c4.y);
    float k2 = __fadd_rn(__fsub_rn(S, __fmul_rn(2.0f, m2)), c4.z);
    float k3 = __fadd_rn(__fsub_rn(S, __fmul_rn(2.0f, m3)), c4.w);
    ins4u(((u64)__float_as_uint(k0) << 32) | (unsigned)(j + 0), b4);
    ins4u(((u64)__float_as_uint(k1) << 32) | (unsigned)(j + 1), b4);
    ins4u(((u64)__float_as_uint(k2) << 32) | (unsigned)(j + 2), b4);
    ins4u(((u64)__float_as_uint(k3) << 32) | (unsigned)(j + 3), b4);
  }

  // ---- wave butterfly all-reduce of top-4 (exact lex; lists disjoint at every level)
#pragma unroll
  for (int m = 1; m < 64; m <<= 1) {
    u64 o0 = shflx64(b4[0], m);
    u64 o1 = shflx64(b4[1], m);
    u64 o2 = shflx64(b4[2], m);
    u64 o3 = shflx64(b4[3], m);
    ins4u(o0, b4);
    ins4u(o1, b4);
    ins4u(o2, b4);
    ins4u(o3, b4);
  }

  // ---- mse D-loop, register-resident, shuffle reduce (bit-exact FROZEN chain).
  // R20: per-beam prefix fold pre[m] = fl-chain of cb[tpl[0..it]] (shared by all 4
  // candidates); candidate row is added LAST in the frozen chain, so
  // q = __fadd_rn(pre, cb[cand]) is BIT-IDENTICAL to the original left-fold.
  {
    float pre[4];
#pragma unroll
    for (int m = 0; m < 4; ++m) {
      int d = l + m * 64;
      float q = cb[(size_t)tup_s[b][0] * D + d];
      for (int a = 1; a <= it; ++a) q = __fadd_rn(q, cb[(size_t)tup_s[b][a] * D + d]);
      pre[m] = q;
    }
#pragma unroll
    for (int pi = 0; pi < 4; ++pi) {
      const int p = b * 4 + pi;
      const int cnd = (int)(b4[pi] & 0xFFFFFFFFULL);
      if (l == 0) {
        for (int a = 0; a < NSTAGES; ++a) primes[p][a] = tup_s[b][a];
        primes[p][it + 1] = cnd;
      }
      float v[4];
#pragma unroll
      for (int m = 0; m < 4; ++m) {
        int d = l + m * 64;
        float q = __fadd_rn(pre[m], cb[(size_t)cnd * D + d]);
        float dv = __fsub_rn(x[(size_t)s * D + d], q);
        v[m] = __fmul_rn(dv, dv);
      }
      float u0 = __shfl_xor(v[0], 32, 64);
      float u1 = __shfl_xor(v[1], 32, 64);
      float u2 = __shfl_xor(v[2], 32, 64);
      float u3 = __shfl_xor(v[3], 32, 64);
      float r0 = __fadd_rn(v[0], u0);
      r0 = __fadd_rn(r0, v[1]);
      r0 = __fadd_rn(r0, u1);
      r0 = __fadd_rn(r0, v[2]);
      r0 = __fadd_rn(r0, u2);
      r0 = __fadd_rn(r0, v[3]);
      r0 = __fadd_rn(r0, u3);
      float a8  = __shfl(r0, l + 8, 64);
      float a16 = __shfl(r0, l + 16, 64);
      float a24 = __shfl(r0, l + 24, 64);
      float w = __fadd_rn(__fadd_rn(__fadd_rn(r0, a8), a16), a24);
      float w0 = __shfl(w, 0, 64), w1 = __shfl(w, 1, 64);
      float w2 = __shfl(w, 2, 64), w3 = __shfl(w, 3, 64);
      float w4 = __shfl(w, 4, 64), w5 = __shfl(w, 5, 64);
      float w6 = __shfl(w, 6, 64), w7 = __shfl(w, 7, 64);
      float s0 = __fadd_rn(w0, w4);
      float s1 = __fadd_rn(w1, w5);
      float s2 = __fadd_rn(w2, w6);
      float s3 = __fadd_rn(w3, w7);
      float t0 = __fadd_rn(s0, s2);
      float t1 = __fadd_rn(s1, s3);
      float S2 = __fadd_rn(t0, t1);
      if (l == 0) msek[p] = __fmul_rn(S2, 0.00390625f);  // /256 exact
    }
  }
  __syncthreads();   // barrier 2: msek + primes visible to t==0

  if (t == 0) {
    if (it < NSTAGES - 2) {
      bool taken[16] = {false};
      int  newt[BEAM_W][NSTAGES];
      for (int rr2 = 0; rr2 < BEAM_W; ++rr2) {
        int bp = -1; float bk = 0.0f;
        for (int p = 0; p < 16; ++p) {
          if (taken[p]) continue;
          if (bp < 0 || msek[p] < bk) { bk = msek[p]; bp = p; }  // strict <: lowest p wins ties
        }
        taken[bp] = true;
        for (int a = 0; a < NSTAGES; ++a) newt[rr2][a] = primes[bp][a];
      }
      for (int rr2 = 0; rr2 < BEAM_W; ++rr2)
        for (int a = 0; a < NSTAGES; ++a)
          tuples[(s * BEAM_W + rr2) * NSTAGES + a] = newt[rr2][a];
    } else {
      int bp = 0; float bk = msek[0];
      for (int p = 1; p < 16; ++p)
        if (msek[p] < bk) { bk = msek[p]; bp = p; }   // argmin: first lowest
      for (int a = 0; a < NSTAGES; ++a) best[s * NSTAGES + a] = primes[bp][a];
    }
  }
}

// ---------------- expand 16 tuples, mse via VF8/IC4 reduce, select (legacy path only)
__global__ __launch_bounds__(256) void mse_select(const float* __restrict__ x,
                                                  const float* __restrict__ cb,
                                                  const int* __restrict__ cand,
                                                  int it,
                                                  int* __restrict__ tuples,
                                                  int* __restrict__ best) {
  const int s = blockIdx.x, tid = threadIdx.x;
  const int wv = tid >> 6, lane = tid & 63;
  __shared__ float buf[4][256];
  __shared__ float rr[4][32];
  __shared__ float msek[16];
  __shared__ int   primes[16][NSTAGES];
  const int L = it + 2;

  for (int pi = 0; pi < 4; ++pi) {
    const int p = wv * 4 + pi;
    const int b = p >> 2, c = p & 3;
    int tpl[NSTAGES];
    for (int a = 0; a < NSTAGES; ++a) tpl[a] = tuples[(s * BEAM_W + b) * NSTAGES + a];
    tpl[it + 1] = cand[(s * BEAM_W + b) * BEAM_W + c];
    if (lane == 0)
      for (int a = 0; a < NSTAGES; ++a) primes[p][a] = tpl[a];
    for (int d = lane; d < D; d += 64) {
      float q = cb[(size_t)tpl[0] * D + d];
      for (int a = 1; a < L; ++a) q = __fadd_rn(q, cb[(size_t)tpl[a] * D + d]);
      float v = __fsub_rn(x[(size_t)s * D + d], q);
      buf[wv][d] = __fmul_rn(v, v);
    }
    __syncthreads();
    if (lane < 32) {
      float r = buf[wv][lane];
      for (int i = 32; i < 256; i += 32) r = __fadd_rn(r, buf[wv][i + lane]);
      rr[wv][lane] = r;
    }
    __syncthreads();
    if (lane == 0) {
      float w[8];
#pragma unroll
      for (int j = 0; j < 8; ++j)
        w[j] = __fadd_rn(__fadd_rn(__fadd_rn(rr[wv][j], rr[wv][8 + j]), rr[wv][16 + j]),
                         rr[wv][24 + j]);
      float s0 = __fadd_rn(w[0], w[4]);
      float s1 = __fadd_rn(w[1], w[5]);
      float s2 = __fadd_rn(w[2], w[6]);
      float s3 = __fadd_rn(w[3], w[7]);
      float t0 = __fadd_rn(s0, s2);
      float t1 = __fadd_rn(s1, s3);
      float S2 = __fadd_rn(t0, t1);
      msek[p] = __fmul_rn(S2, 0.00390625f);
    }
    __syncthreads();
  }

  if (tid == 0) {
    if (it < NSTAGES - 2) {
      bool taken[16] = {false};
      int  newt[BEAM_W][NSTAGES];
      for (int r = 0; r < BEAM_W; ++r) {
        int bp = -1; float bk = 0.0f;
        for (int p = 0; p < 16; ++p) {
          if (taken[p]) continue;
          if (bp < 0 || msek[p] < bk) { bk = msek[p]; bp = p; }
        }
        taken[bp] = true;
        for (int a = 0; a < NSTAGES; ++a) newt[r][a] = primes[bp][a];
      }
      for (int r = 0; r < BEAM_W; ++r)
        for (int a = 0; a < NSTAGES; ++a) tuples[(s * BEAM_W + r) * NSTAGES + a] = newt[r][a];
    } else {
      int bp = 0; float bk = msek[0];
      for (int p = 1; p < 16; ++p)
        if (msek[p] < bk) { bk = msek[p]; bp = p; }
      for (int a = 0; a < NSTAGES; ++a) best[s * NSTAGES + a] = primes[bp][a];
    }
  }
}

// ---------------- zero the 'used' region of d_out
__global__ void zero_used(float* __restrict__ u) {
  int t = blockIdx.x * 256 + threadIdx.x;
  if (t < SK) u[t] = 0.0f;
}

// ---------------- epilogue: nsvq (or quantized) + used bitmap
__global__ __launch_bounds__(256) void finalize_kernel(const float* __restrict__ x,
                                                       const float* __restrict__ cb,
                                                       const float* __restrict__ rvec,
                                                       const int* __restrict__ best,
                                                       const int* __restrict__ tmode,
                                                       float* __restrict__ out) {
  const int i = blockIdx.x;
  const int t = threadIdx.x;
  __shared__ double s1[256], s2[256];
  const int b0 = best[i * 4 + 0], b1 = best[i * 4 + 1];
  const int b2 = best[i * 4 + 2], b3 = best[i * 4 + 3];
  float q = ((cb[(size_t)b0 * D + t] + cb[(size_t)b1 * D + t]) + cb[(size_t)b2 * D + t]) +
            cb[(size_t)b3 * D + t];
  float xv = x[(size_t)i * D + t];
  float rv = rvec[(size_t)i * D + t];
  float df = xv - q;
  s1[t] = (double)df * (double)df;
  s2[t] = (double)rv * (double)rv;
  __syncthreads();
  for (int off = 128; off; off >>= 1) {
    if (t < off) { s1[t] += s1[t + off]; s2[t] += s2[t + off]; }
    __syncthreads();
  }
  float nh = sqrtf((float)s1[0]);
  float nr = sqrtf((float)s2[0]);
  float ratio = nh / nr + 1e-12f;
  out[(size_t)i * D + t] = (*tmode != 0) ? (xv + ratio * rv) : q;
  if (t < 4) out[(size_t)NB * D + best[i * 4 + t]] = 1.0f;
}

// ----------------------------------------------------------------
extern "C" void kernel_launch(void* const* d_in, const int* in_sizes, int n_in,
                              void* d_out, int out_size, void* d_ws, size_t ws_size,
                              hipStream_t stream) {
  const float* x   = (const float*)d_in[0];
  const float* cb  = (const float*)d_in[1];
  const float* rv  = (const float*)d_in[2];
  const int*   tm  = (const int*)d_in[3];
  float*       out = (float*)d_out;

  const size_t XC_BYTES    = (size_t)NB * SK * sizeof(float);                 // 64 MB
  const size_t G_BYTES     = (size_t)SK * SK * sizeof(float);                 // 64 MB
  const size_t BT_BYTES    = (size_t)D * SK * sizeof(float);                  // 4 MB
  const size_t AT0_BYTES   = (size_t)D * NB * sizeof(float);                  // 4 MB
  const size_t ATL_BYTES   = (size_t)D * NB * BEAM_W * sizeof(float);         // 16 MB (legacy)
  const size_t PKI0_BYTES  = (size_t)NCBLK * NB * BEAM_W * sizeof(u64);       // 2.1 MB
  const size_t PKIL_BYTES  = (size_t)NCBLK * NB * BEAM_W * 4 * sizeof(u64);   // 8.4 MB (legacy)
  const size_t S_BYTES     = (size_t)NB * BEAM_W * sizeof(float);
  const size_t CB2_BYTES   = (size_t)SK * sizeof(float);
  const size_t TUP_BYTES   = (size_t)NB * BEAM_W * NSTAGES * sizeof(int);
  const size_t CAND_BYTES  = (size_t)NB * BEAM_W * BEAM_W * sizeof(int);
  const size_t BEST_BYTES  = (size_t)NB * NSTAGES * sizeof(int);
  const size_t SMALL = S_BYTES + CB2_BYTES + TUP_BYTES + CAND_BYTES + BEST_BYTES;

  const size_t NEW_TOTAL    = XC_BYTES + G_BYTES + BT_BYTES + AT0_BYTES + PKI0_BYTES + SMALL;
  const size_t LEGACY_TOTAL = PKIL_BYTES + BT_BYTES + ATL_BYTES + SMALL;

  if (ws_size >= NEW_TOTAL) {
    // ---- fast path: step-0 GEMM first (R14 order), THEN G pipeline, then key_select
    char* ws = (char*)d_ws;
    float* XC   = (float*)ws;  ws += XC_BYTES;
    float* G    = (float*)ws;  ws += G_BYTES;
    float* cbT  = (float*)ws;  ws += BT_BYTES;
    float* AT   = (float*)ws;  ws += AT0_BYTES;
    u64*   pki  = (u64*)ws;    ws += PKI0_BYTES;
    float* Srow = (float*)ws;  ws += S_BYTES;
    float* cb2  = (float*)ws;  ws += CB2_BYTES;
    int*   tup  = (int*)ws;    ws += TUP_BYTES;
    int*   cand = (int*)ws;    ws += CAND_BYTES;
    int*   best = (int*)ws;

    cb2_pw<<<SK / 256, 256, 0, stream>>>(cb, cb2);
    s0_pw<<<NB / 256, 256, 0, stream>>>(x, Srow);
    transpose_rem<<<dim3(SK / 64, D / 64), 256, 0, stream>>>(cb, cb, tup, 0, 1, SK, cbT);
    transpose_rem<<<dim3(NB / 64, D / 64), 256, 0, stream>>>(x, cb, tup, 0, 1, NB, AT);

    gemm_fused<<<dim3(NCBLK, NB / RB), 256, 0, stream>>>(AT, cbT, Srow, cb2, tup, 0, 1, NB,
                                                         pki, XC);             // step0 + XC
    reduce_top4<<<NB / 256, 256, 0, stream>>>(pki, NB, 1, tup, cand);

    gemm_plain<<<dim3(NCBLK, SK / RB), 256, 0, stream>>>(cbT, cbT, SK, 1, G);  // upper+diag
    mirror_g<<<dim3(SK / 64, SK / 64), 256, 0, stream>>>(G);                   // lower tiles

    for (int it = 0; it < NSTAGES - 1; ++it)
      key_select<<<NB, 256, 0, stream>>>(XC, G, cb2, x, cb, it, tup, best);

    zero_used<<<SK / 256, 256, 0, stream>>>(out + (size_t)NB * D);
    finalize_kernel<<<NB, 256, 0, stream>>>(x, cb, rv, best, tm, out);
    return;
  }

  if (ws_size < LEGACY_TOTAL) return;
  // ---------------- legacy path (R0-proven) ----------------
  char* ws = (char*)d_ws;
  u64*   pki  = (u64*)ws;    ws += PKIL_BYTES;
  float* cbT  = (float*)ws;  ws += BT_BYTES;
  float* AT   = (float*)ws;  ws += ATL_BYTES;
  float* Srow = (float*)ws;  ws += S_BYTES;
  float* cb2  = (float*)ws;  ws += CB2_BYTES;
  int*   tup  = (int*)ws;    ws += TUP_BYTES;
  int*   cand = (int*)ws;    ws += CAND_BYTES;
  int*   best = (int*)ws;

  cb2_pw<<<SK / 256, 256, 0, stream>>>(cb, cb2);
  s0_pw<<<NB / 256, 256, 0, stream>>>(x, Srow);
  transpose_rem<<<dim3(SK / 64, D / 64), 256, 0, stream>>>(cb, cb, tup, 0, 1, SK, cbT);
  transpose_rem<<<dim3(NB / 64, D / 64), 256, 0, stream>>>(x, cb, tup, 0, 1, NB, AT);

  gemm_fused<<<dim3(NCBLK, NB / RB), 256, 0, stream>>>(AT, cbT, Srow, cb2, tup, 0, 1, NB,
                                                       pki, nullptr);
  reduce_top4<<<NB / 256, 256, 0, stream>>>(pki, NB, 1, tup, cand);

  for (int it = 0; it < NSTAGES - 1; ++it) {
    srow_pw<<<(NB * BEAM_W) / 256, 256, 0, stream>>>(x, cb, tup, it, Srow);
    transpose_rem<<<dim3(NB * BEAM_W / 64, D / 64), 256, 0, stream>>>(x, cb, tup, it, 0,
                                                                      NB * BEAM_W, AT);
    gemm_fused<<<dim3(NCBLK, (NB * BEAM_W) / RB), 256, 0, stream>>>(
        AT, cbT, Srow, cb2, tup, it, 0, NB * BEAM_W, pki, nullptr);
    reduce_top4<<<(NB * BEAM_W) / 256, 256, 0, stream>>>(pki, NB * BEAM_W, 0, tup, cand);
    mse_select<<<NB, 256, 0, stream>>>(x, cb, cand, it, tup, best);
  }

  zero_used<<<SK / 256, 256, 0, stream>>>(out + (size_t)NB * D);
  finalize_kernel<<<NB, 256, 0, stream>>>(x, cb, rv, best, tm, out);
}